// Round 4
// baseline (389.678 us; speedup 1.0000x reference)
//
#include <hip/hip_runtime.h>
#include <hip/hip_fp16.h>
#include <math.h>

#define N_NODES 50000
#define N_EDGES 800000
#define ET (N_EDGES + N_NODES)   // edges + self-loops
#define IN_DIM 128
#define HID 64
#define HEADS 4
#define C1 (HEADS * HID)         // 256
#define OUT_DIM 128
#define NEG_SLOPE 0.2f
#define MTILES 3125              // 50000 / 16 row-tiles
#define SCAN_B 1024
#define NSCB 49                  // ceil(50000/1024)

typedef _Float16 h8 __attribute__((ext_vector_type(8)));
typedef float f4 __attribute__((ext_vector_type(4)));
typedef unsigned short u16;

__device__ __forceinline__ float leaky(float v) { return fmaxf(v, NEG_SLOPE * v); }
__device__ __forceinline__ float elu(float v) { return v > 0.0f ? v : expm1f(v); }

// One v_fma_mix_f32 per feature: acc.f32 += h.f16 * w.f32 (no extract/convert insts)
__device__ __forceinline__ void fma_mix8(float* acc, h8 v, float w) {
    union { h8 h; int i[4]; } u; u.h = v;
#pragma unroll
    for (int k = 0; k < 4; ++k) {
        asm("v_fma_mix_f32 %0, %1, %2, %0 op_sel:[0,0,0] op_sel_hi:[1,0,0]"
            : "+v"(acc[2 * k]) : "v"(u.i[k]), "v"(w));
        asm("v_fma_mix_f32 %0, %1, %2, %0 op_sel:[1,0,0] op_sel_hi:[1,0,0]"
            : "+v"(acc[2 * k + 1]) : "v"(u.i[k]), "v"(w));
    }
}

// ================= prep: weight transpose->fp16 + dst histogram =================
__global__ void prep_kernel(const float* __restrict__ W1, const float* __restrict__ W2,
                            const int* __restrict__ dst, __half* __restrict__ w1t,
                            __half* __restrict__ w2t, int* __restrict__ cnt) {
    const int tid = blockIdx.x * blockDim.x + threadIdx.x;
    const int np = gridDim.x * blockDim.x;
    for (int i = tid; i < IN_DIM * C1; i += np) {
        int k1 = i >> 8, n1 = i & 255;
        w1t[n1 * IN_DIM + k1] = __float2half(W1[i]);
        int k2 = i >> 7, n2 = i & 127;
        w2t[n2 * C1 + k2] = __float2half(W2[i]);
    }
    for (int i = tid; i < ET; i += np) {
        int d = (i < N_EDGES) ? dst[i] : i - N_EDGES;
        atomicAdd(&cnt[d], 1);
    }
}

// ================= CSR scan + scatter =================
__global__ void scan_local(const int* __restrict__ cnt, int* __restrict__ lscan,
                           int* __restrict__ bsum) {
    __shared__ int wsum[16];
    const int t = threadIdx.x, lane = t & 63, wv = t >> 6;
    int idx = blockIdx.x * SCAN_B + t;
    int v = (idx < N_NODES) ? cnt[idx] : 0;
    int sc = v;
#pragma unroll
    for (int o = 1; o < 64; o <<= 1) {
        int u = __shfl_up(sc, o);
        if (lane >= o) sc += u;
    }
    if (lane == 63) wsum[wv] = sc;
    __syncthreads();
    if (t == 0) {
        int run = 0;
#pragma unroll
        for (int w = 0; w < 16; ++w) { int s = wsum[w]; wsum[w] = run; run += s; }
        bsum[blockIdx.x] = run;
    }
    __syncthreads();
    if (idx < N_NODES) lscan[idx] = sc + wsum[wv];  // inclusive within block
}

__global__ void scan_bsum(int* __restrict__ bsum) {  // 1 block, 64 thr
    const int t = threadIdx.x;
    int v = (t < NSCB) ? bsum[t] : 0;
    int sc = v;
#pragma unroll
    for (int o = 1; o < 64; o <<= 1) {
        int u = __shfl_up(sc, o);
        if (t >= o) sc += u;
    }
    if (t < NSCB) bsum[t] = sc - v;  // exclusive
}

__global__ void scan_final(const int* __restrict__ cnt, const int* __restrict__ lscan,
                           const int* __restrict__ bsum, int* __restrict__ rp,
                           int* __restrict__ cursor) {
    int idx = blockIdx.x * SCAN_B + threadIdx.x;
    if (idx == 0) rp[0] = 0;
    if (idx >= N_NODES) return;
    int inc = lscan[idx] + bsum[idx >> 10];
    rp[idx + 1] = inc;
    cursor[idx] = inc - cnt[idx];
}

__global__ void scatter_kernel(const int* __restrict__ src, const int* __restrict__ dst,
                               int* __restrict__ cursor, u16* __restrict__ cs16) {
    int i = blockIdx.x * blockDim.x + threadIdx.x;
    if (i >= ET) return;
    int s, d;
    if (i < N_EDGES) { s = src[i]; d = dst[i]; } else { s = d = i - N_EDGES; }
    int pos = atomicAdd(&cursor[d], 1);
    cs16[pos] = (u16)s;                 // src < 50000 fits u16
}

// ================= GEMM1 (MFMA fp16, SWAPPED operands) + fused attention dots ===
// mfma(w_frag, x_frag) -> D[col, node]: lane owns node m0+(lane&15) and 4 consecutive
// cols nt*16+(lane>>4)*4+r. Epilogue: 16x 8-B packed h-stores, coalesced dot writes.
// h written HEAD-MAJOR: hm[head][node][64] fp16. as1/ad1 head-planar [head][node].
__global__ __launch_bounds__(256) void gemm1_mfma(
        const float* __restrict__ x, const __half* __restrict__ w1t,
        const float* __restrict__ aws, const float* __restrict__ awd,
        __half* __restrict__ hm, float* __restrict__ as1m, float* __restrict__ ad1m) {
    const int tile = blockIdx.x * 4 + (threadIdx.x >> 6);
    if (tile >= MTILES) return;
    const int lane = threadIdx.x & 63;
    const int m0 = tile * 16, lm = lane & 15, lq = lane >> 4;
    const int node = m0 + lm;
    h8 afrag[4];
    const float4* xrow = (const float4*)(x + (size_t)node * IN_DIM + lq * 8);
#pragma unroll
    for (int kt = 0; kt < 4; ++kt) {
        float4 a = xrow[kt * 8];
        float4 b = xrow[kt * 8 + 1];
        union { h8 v; __half2 p[4]; } u;
        u.p[0] = __floats2half2_rn(a.x, a.y);
        u.p[1] = __floats2half2_rn(a.z, a.w);
        u.p[2] = __floats2half2_rn(b.x, b.y);
        u.p[3] = __floats2half2_rn(b.z, b.w);
        afrag[kt] = u.v;
    }
    f4 acc[16];
#pragma unroll
    for (int nt = 0; nt < 16; ++nt) acc[nt] = (f4){0.f, 0.f, 0.f, 0.f};
#pragma unroll
    for (int nt = 0; nt < 16; ++nt) {
        const h8* brow = (const h8*)(w1t + (size_t)(nt * 16 + lm) * IN_DIM + lq * 8);
#pragma unroll
        for (int kt = 0; kt < 4; ++kt)
            acc[nt] = __builtin_amdgcn_mfma_f32_16x16x32_f16(brow[kt * 4], afrag[kt],
                                                             acc[nt], 0, 0, 0);  // SWAPPED
    }
    float sS[4] = {0.f, 0.f, 0.f, 0.f}, sD[4] = {0.f, 0.f, 0.f, 0.f};
#pragma unroll
    for (int nt = 0; nt < 16; ++nt) {
        const int col0 = nt * 16 + lq * 4;
        float4 wa4 = ((const float4*)aws)[nt * 4 + lq];
        float4 wd4 = ((const float4*)awd)[nt * 4 + lq];
        union { __half2 h2[2]; int2 i2; } u;
        u.h2[0] = __floats2half2_rn(acc[nt][0], acc[nt][1]);
        u.h2[1] = __floats2half2_rn(acc[nt][2], acc[nt][3]);
        const int head = col0 >> 6;
        *(int2*)((char*)hm + ((size_t)head * N_NODES + node) * 128 + (col0 & 63) * 2) = u.i2;
        sS[nt >> 2] += acc[nt][0] * wa4.x + acc[nt][1] * wa4.y +
                       acc[nt][2] * wa4.z + acc[nt][3] * wa4.w;
        sD[nt >> 2] += acc[nt][0] * wd4.x + acc[nt][1] * wd4.y +
                       acc[nt][2] * wd4.z + acc[nt][3] * wd4.w;
    }
#pragma unroll
    for (int h = 0; h < 4; ++h) {
        sS[h] += __shfl_xor(sS[h], 16); sS[h] += __shfl_xor(sS[h], 32);
        sD[h] += __shfl_xor(sD[h], 16); sD[h] += __shfl_xor(sD[h], 32);
    }
    if (lq == 0) {
#pragma unroll
        for (int h = 0; h < 4; ++h) {
            as1m[h * N_NODES + node] = sS[h];
            ad1m[h * N_NODES + node] = sD[h];
        }
    }
}

// ================= GEMM2 (MFMA fp16, SWAPPED operands) + fused dots (1 head) =====
__global__ __launch_bounds__(256) void gemm2_mfma(
        const __half* __restrict__ ah, const __half* __restrict__ w2t,
        const float* __restrict__ aws, const float* __restrict__ awd,
        __half* __restrict__ h, float* __restrict__ as2, float* __restrict__ ad2) {
    const int tile = blockIdx.x * 4 + (threadIdx.x >> 6);
    if (tile >= MTILES) return;
    const int lane = threadIdx.x & 63;
    const int m0 = tile * 16, lm = lane & 15, lq = lane >> 4;
    const int node = m0 + lm;
    h8 afrag[8];
    const h8* arow = (const h8*)(ah + (size_t)node * C1 + lq * 8);
#pragma unroll
    for (int kt = 0; kt < 8; ++kt) afrag[kt] = arow[kt * 4];
    f4 acc[8];
#pragma unroll
    for (int nt = 0; nt < 8; ++nt) acc[nt] = (f4){0.f, 0.f, 0.f, 0.f};
#pragma unroll
    for (int nt = 0; nt < 8; ++nt) {
        const h8* brow = (const h8*)(w2t + (size_t)(nt * 16 + lm) * C1 + lq * 8);
#pragma unroll
        for (int kt = 0; kt < 8; ++kt)
            acc[nt] = __builtin_amdgcn_mfma_f32_16x16x32_f16(brow[kt * 4], afrag[kt],
                                                             acc[nt], 0, 0, 0);  // SWAPPED
    }
    float sS = 0.f, sD = 0.f;
#pragma unroll
    for (int nt = 0; nt < 8; ++nt) {
        const int col0 = nt * 16 + lq * 4;
        float4 wa4 = ((const float4*)aws)[nt * 4 + lq];
        float4 wd4 = ((const float4*)awd)[nt * 4 + lq];
        union { __half2 h2[2]; int2 i2; } u;
        u.h2[0] = __floats2half2_rn(acc[nt][0], acc[nt][1]);
        u.h2[1] = __floats2half2_rn(acc[nt][2], acc[nt][3]);
        *(int2*)((char*)h + (size_t)node * (OUT_DIM * 2) + col0 * 2) = u.i2;
        sS += acc[nt][0] * wa4.x + acc[nt][1] * wa4.y +
              acc[nt][2] * wa4.z + acc[nt][3] * wa4.w;
        sD += acc[nt][0] * wd4.x + acc[nt][1] * wd4.y +
              acc[nt][2] * wd4.z + acc[nt][3] * wd4.w;
    }
    sS += __shfl_xor(sS, 16); sS += __shfl_xor(sS, 32);
    sD += __shfl_xor(sD, 16); sD += __shfl_xor(sD, 32);
    if (lq == 0) {
        as2[node] = sS;
        ad2[node] = sD;
    }
}

// ================= alpha precompute, layer 1 (head-planar) =================
// Half-wave per node: alphaP[h][pos] = exp(leaky(as1[h][src] + ad1[h][d])) for all
// 4 heads in one pass. Removes exp + as-gather from agg1's staging entirely.
__global__ __launch_bounds__(256) void alpha1_kernel(
        const int* __restrict__ rp, const u16* __restrict__ cs16,
        const float* __restrict__ as1m, const float* __restrict__ ad1m,
        float* __restrict__ alphaP) {
    const int hw = threadIdx.x >> 5, li = threadIdx.x & 31;
    const int d = blockIdx.x * 8 + hw;
    const int e0 = rp[d], deg = rp[d + 1] - e0;
    const float a0 = ad1m[d];
    const float a1 = ad1m[N_NODES + d];
    const float a2 = ad1m[2 * N_NODES + d];
    const float a3 = ad1m[3 * N_NODES + d];
    for (int idx = li; idx < deg; idx += 32) {
        int p = e0 + idx;
        int s = cs16[p];
        alphaP[p]            = __expf(leaky(as1m[s] + a0));
        alphaP[ET + p]       = __expf(leaky(as1m[N_NODES + s] + a1));
        alphaP[2 * ET + p]   = __expf(leaky(as1m[2 * N_NODES + s] + a2));
        alphaP[3 * ET + p]   = __expf(leaky(as1m[3 * N_NODES + s] + a3));
    }
}

// ================= fused softmax + aggregate, layer 1, HEAD-SPLIT (G=4) ==========
// head = blockIdx & 3 -> XCD round-robin gives each XCD a single 6.4-MB head table.
// Staging is lean (u16 src + precomputed f32 alpha, no exp/gather). Half-wave per
// (node, head): 4 edge-slots x 8 feat-lanes; 4 gathers in flight (16-edge unroll).
__global__ __launch_bounds__(256) void aggregate1_fused(
        const int* __restrict__ rp, const u16* __restrict__ cs16,
        const float* __restrict__ alphaP, const __half* __restrict__ hm,
        const float* __restrict__ b1, __half* __restrict__ out1h) {
    __shared__ int2 stg[8][32];      // [halfwave][edge] = {row byte off, alpha bits}
    const int head = blockIdx.x & 3, g = blockIdx.x >> 2;
    const int hw = threadIdx.x >> 5, li = threadIdx.x & 31;
    const int d = g * 8 + hw;
    const int e0 = rp[d], deg = rp[d + 1] - e0;  // deg >= 1 (self-loop)
    const float* ap = alphaP + (size_t)head * ET;
    const char* hb = (const char*)hm + (size_t)head * N_NODES * 128;
    const int es = li >> 3, fl = li & 7;
    const int lbyte = fl * 16;       // 8 fp16 = 16 B; 8 lanes cover the 128-B head row
    float acc[8] = {0.f, 0.f, 0.f, 0.f, 0.f, 0.f, 0.f, 0.f};
    float dsum = 0.f;
    for (int c0 = 0; c0 < deg; c0 += 32) {
        const int clen = min(32, deg - c0);
        int idx = c0 + li;
        bool valid = idx < deg;
        int s = valid ? (int)cs16[e0 + idx] : 0;
        float a = valid ? ap[e0 + idx] : 0.f;
        stg[hw][li] = make_int2(s << 7, __float_as_int(a));  // head row = 128 B
        dsum += a;
        __builtin_amdgcn_wave_barrier();  // DS in-order per wave; block compiler reordering
        int j = 0;
        for (; j + 16 <= clen; j += 16) { // 16 edges per iteration, 4 loads in flight
            int2 p0 = stg[hw][j + es];
            int2 p1 = stg[hw][j + 4 + es];
            int2 p2 = stg[hw][j + 8 + es];
            int2 p3 = stg[hw][j + 12 + es];
            h8 v0 = *(const h8*)(hb + p0.x + lbyte);
            h8 v1 = *(const h8*)(hb + p1.x + lbyte);
            h8 v2 = *(const h8*)(hb + p2.x + lbyte);
            h8 v3 = *(const h8*)(hb + p3.x + lbyte);
            fma_mix8(acc, v0, __int_as_float(p0.y));
            fma_mix8(acc, v1, __int_as_float(p1.y));
            fma_mix8(acc, v2, __int_as_float(p2.y));
            fma_mix8(acc, v3, __int_as_float(p3.y));
        }
        for (; j < clen; j += 4) {
            // slots up to 31 always initialized (alpha=0 when invalid) -> safe
            int2 p0 = stg[hw][j + es];
            h8 v0 = *(const h8*)(hb + p0.x + lbyte);
            fma_mix8(acc, v0, __int_as_float(p0.y));
        }
        __builtin_amdgcn_wave_barrier();
    }
    // combine the 4 edge-slot groups (masks 8,16 stay within the 32-lane half)
#pragma unroll
    for (int f = 0; f < 8; ++f) {
        acc[f] += __shfl_xor(acc[f], 8);
        acc[f] += __shfl_xor(acc[f], 16);
    }
#pragma unroll
    for (int o = 16; o > 0; o >>= 1) dsum += __shfl_xor(dsum, o);
    if (es == 0) {                   // lanes 0..7 of the half-wave
        float inv = 1.0f / (dsum + 1e-16f);
        float4 bA = ((const float4*)b1)[head * 16 + fl * 2];
        float4 bB = ((const float4*)b1)[head * 16 + fl * 2 + 1];
        h8 o;
        o[0] = (_Float16)elu(acc[0] * inv + bA.x);
        o[1] = (_Float16)elu(acc[1] * inv + bA.y);
        o[2] = (_Float16)elu(acc[2] * inv + bA.z);
        o[3] = (_Float16)elu(acc[3] * inv + bA.w);
        o[4] = (_Float16)elu(acc[4] * inv + bB.x);
        o[5] = (_Float16)elu(acc[5] * inv + bB.y);
        o[6] = (_Float16)elu(acc[6] * inv + bB.z);
        o[7] = (_Float16)elu(acc[7] * inv + bB.w);
        *(h8*)((char*)out1h + (size_t)d * 512 + head * 128 + lbyte) = o;
    }
}

// ================= fused softmax + aggregate + bias + L2-normalize, layer 2 ======
// HALF-WAVE per node; row = 128 fp16 = 256 B = 16 lanes x 16 B; q in {0,1}.
// 4 gathers in flight per lane (8 edges per iteration).
__global__ __launch_bounds__(256) void aggregate2_fused(
        const int* __restrict__ rp, const u16* __restrict__ cs16,
        const __half* __restrict__ h2h, const float* __restrict__ as2,
        const float* __restrict__ ad2, const float* __restrict__ b2,
        float* __restrict__ out) {
    __shared__ int2 stg[8][32];      // [halfwave][edge] = {row byte offset, alpha bits}
    const int hw = threadIdx.x >> 5, li = threadIdx.x & 31;
    const int d = blockIdx.x * 8 + hw;
    const int e0 = rp[d], deg = rp[d + 1] - e0;
    const float adv = ad2[d];
    const int q = li >> 4, lo = li & 15;
    const int lbyte = lo * 16;       // 8 fp16
    const char* hbase = (const char*)h2h;
    float acc[8] = {0.f, 0.f, 0.f, 0.f, 0.f, 0.f, 0.f, 0.f};
    float dsum = 0.f;
    for (int c0 = 0; c0 < deg; c0 += 32) {
        const int clen = min(32, deg - c0);
        int idx = c0 + li;
        bool valid = idx < deg;
        int s = valid ? (int)cs16[e0 + idx] : 0;
        float xv = valid ? __expf(leaky(as2[s] + adv)) : 0.f;
        stg[hw][li] = make_int2(s << 8, __float_as_int(xv));  // row = 256 B
        dsum += xv;
        __builtin_amdgcn_wave_barrier();
        int j = 0;
        for (; j + 8 <= clen; j += 8) {   // 8 edges per iteration, 4 loads in flight
            int2 p0 = stg[hw][j + q];
            int2 p1 = stg[hw][j + 2 + q];
            int2 p2 = stg[hw][j + 4 + q];
            int2 p3 = stg[hw][j + 6 + q];
            h8 v0 = *(const h8*)(hbase + p0.x + lbyte);
            h8 v1 = *(const h8*)(hbase + p1.x + lbyte);
            h8 v2 = *(const h8*)(hbase + p2.x + lbyte);
            h8 v3 = *(const h8*)(hbase + p3.x + lbyte);
            fma_mix8(acc, v0, __int_as_float(p0.y));
            fma_mix8(acc, v1, __int_as_float(p1.y));
            fma_mix8(acc, v2, __int_as_float(p2.y));
            fma_mix8(acc, v3, __int_as_float(p3.y));
        }
        for (; j < clen; j += 2) {
            int2 p0 = stg[hw][j + q];
            h8 v0 = *(const h8*)(hbase + p0.x + lbyte);
            fma_mix8(acc, v0, __int_as_float(p0.y));
        }
        __builtin_amdgcn_wave_barrier();
    }
#pragma unroll
    for (int f = 0; f < 8; ++f) acc[f] += __shfl_xor(acc[f], 16);  // combine q=0/1
#pragma unroll
    for (int o = 16; o > 0; o >>= 1) dsum += __shfl_xor(dsum, o);
    if (q == 0) {
        float inv = 1.0f / (dsum + 1e-16f);
        float4 bA = ((const float4*)b2)[lo * 2];
        float4 bB = ((const float4*)b2)[lo * 2 + 1];
        float v0 = acc[0] * inv + bA.x, v1 = acc[1] * inv + bA.y;
        float v2 = acc[2] * inv + bA.z, v3 = acc[3] * inv + bA.w;
        float v4 = acc[4] * inv + bB.x, v5 = acc[5] * inv + bB.y;
        float v6 = acc[6] * inv + bB.z, v7 = acc[7] * inv + bB.w;
        float ss = v0 * v0 + v1 * v1 + v2 * v2 + v3 * v3 +
                   v4 * v4 + v5 * v5 + v6 * v6 + v7 * v7;
#pragma unroll
        for (int o = 1; o < 16; o <<= 1) ss += __shfl_xor(ss, o);  // lanes lo 0-15 group
        float sc = 1.0f / fmaxf(sqrtf(ss), 1e-12f);
        float4* orow = (float4*)((char*)out + (size_t)d * 512 + lo * 32);
        orow[0] = make_float4(v0 * sc, v1 * sc, v2 * sc, v3 * sc);
        orow[1] = make_float4(v4 * sc, v5 * sc, v6 * sc, v7 * sc);
    }
}

extern "C" void kernel_launch(void* const* d_in, const int* in_sizes, int n_in,
                              void* d_out, int out_size, void* d_ws, size_t ws_size,
                              hipStream_t stream) {
    const float* x     = (const float*)d_in[0];
    const int*   edge  = (const int*)d_in[1];
    const int*   src   = edge;
    const int*   dst   = edge + N_EDGES;
    const float* W1    = (const float*)d_in[2];
    const float* aw_s1 = (const float*)d_in[3];
    const float* aw_d1 = (const float*)d_in[4];
    const float* b1    = (const float*)d_in[5];
    const float* W2    = (const float*)d_in[6];
    const float* aw_s2 = (const float*)d_in[7];
    const float* aw_d2 = (const float*)d_in[8];
    const float* b2    = (const float*)d_in[9];
    float* out = (float*)d_out;

    // ---- workspace layout ----
    char* ws = (char*)d_ws;
    size_t off = 0;
    auto alloc = [&](size_t bytes) {
        void* p = ws + off;
        off += (bytes + 255) & ~(size_t)255;
        return p;
    };
    u16*    cs16   = (u16*)alloc((size_t)ET * 2);                   // 1.7 MB
    int*    rp     = (int*)alloc((size_t)(N_NODES + 1) * 4);
    int*    cursor = (int*)alloc((size_t)N_NODES * 4);
    int*    cnt    = (int*)alloc((size_t)N_NODES * 4);
    int*    lscan  = (int*)alloc((size_t)NSCB * SCAN_B * 4);
    int*    bsum   = (int*)alloc((size_t)NSCB * 4);
    float*  as1m   = (float*)alloc((size_t)N_NODES * HEADS * 4);    // head-planar
    float*  ad1m   = (float*)alloc((size_t)N_NODES * HEADS * 4);    // head-planar
    float*  as2    = (float*)alloc((size_t)N_NODES * 4);
    float*  ad2    = (float*)alloc((size_t)N_NODES * 4);
    __half* w1t    = (__half*)alloc((size_t)IN_DIM * C1 * 2);
    __half* w2t    = (__half*)alloc((size_t)C1 * OUT_DIM * 2);
    float*  alphaP = (float*)alloc((size_t)HEADS * ET * 4);         // 13.6 MB
    __half* hm     = (__half*)alloc((size_t)N_NODES * C1 * 2);      // 25.6 MB (reused as h2h)
    __half* out1h  = (__half*)alloc((size_t)N_NODES * C1 * 2);      // 25.6 MB
    __half* h2h    = hm;  // layer-1 head tables dead after aggregate1
    (void)off;

    // Only cnt needs zeroing (atomic histogram).
    hipMemsetAsync(cnt, 0, (size_t)N_NODES * 4, stream);

    const int egrid = (ET + 255) / 256;

    // ---- prep (weight transpose + histogram) + CSR build ----
    prep_kernel<<<1024, 256, 0, stream>>>(W1, W2, dst, w1t, w2t, cnt);
    scan_local<<<NSCB, SCAN_B, 0, stream>>>(cnt, lscan, bsum);
    scan_bsum<<<1, 64, 0, stream>>>(bsum);
    scan_final<<<NSCB, SCAN_B, 0, stream>>>(cnt, lscan, bsum, rp, cursor);
    scatter_kernel<<<egrid, 256, 0, stream>>>(src, dst, cursor, cs16);

    // ---- layer 1 ----
    gemm1_mfma<<<(MTILES + 3) / 4, 256, 0, stream>>>(x, w1t, aw_s1, aw_d1, hm, as1m, ad1m);
    alpha1_kernel<<<N_NODES / 8, 256, 0, stream>>>(rp, cs16, as1m, ad1m, alphaP);
    aggregate1_fused<<<(N_NODES / 8) * HEADS, 256, 0, stream>>>(rp, cs16, alphaP, hm, b1, out1h);

    // ---- layer 2 ----
    gemm2_mfma<<<(MTILES + 3) / 4, 256, 0, stream>>>(out1h, w2t, aw_s2, aw_d2, h2h, as2, ad2);
    aggregate2_fused<<<N_NODES / 8, 256, 0, stream>>>(rp, cs16, h2h, as2, ad2, b2, out);
}

// Round 5
// 363.959 us; speedup vs baseline: 1.0707x; 1.0707x over previous
//
#include <hip/hip_runtime.h>
#include <hip/hip_fp16.h>
#include <math.h>

#define N_NODES 50000
#define N_EDGES 800000
#define ET (N_EDGES + N_NODES)   // edges + self-loops
#define IN_DIM 128
#define HID 64
#define HEADS 4
#define C1 (HEADS * HID)         // 256
#define OUT_DIM 128
#define NEG_SLOPE 0.2f
#define MTILES 3125              // 50000 / 16 row-tiles
#define SCAN_B 1024
#define NSCB 49                  // ceil(50000/1024)

typedef _Float16 h8 __attribute__((ext_vector_type(8)));
typedef float f4 __attribute__((ext_vector_type(4)));

__device__ __forceinline__ float leaky(float v) { return fmaxf(v, NEG_SLOPE * v); }
__device__ __forceinline__ float elu(float v) { return v > 0.0f ? v : expm1f(v); }

// One v_fma_mix_f32 per feature: acc.f32 += h.f16 * w.f32 (no extract/convert insts)
__device__ __forceinline__ void fma_mix8(float* acc, h8 v, float w) {
    union { h8 h; int i[4]; } u; u.h = v;
#pragma unroll
    for (int k = 0; k < 4; ++k) {
        asm("v_fma_mix_f32 %0, %1, %2, %0 op_sel:[0,0,0] op_sel_hi:[1,0,0]"
            : "+v"(acc[2 * k]) : "v"(u.i[k]), "v"(w));
        asm("v_fma_mix_f32 %0, %1, %2, %0 op_sel:[1,0,0] op_sel_hi:[1,0,0]"
            : "+v"(acc[2 * k + 1]) : "v"(u.i[k]), "v"(w));
    }
}

// ================= prep: weight transpose->fp16 + dst histogram =================
__global__ void prep_kernel(const float* __restrict__ W1, const float* __restrict__ W2,
                            const int* __restrict__ dst, __half* __restrict__ w1t,
                            __half* __restrict__ w2t, int* __restrict__ cnt) {
    const int tid = blockIdx.x * blockDim.x + threadIdx.x;
    const int np = gridDim.x * blockDim.x;
    for (int i = tid; i < IN_DIM * C1; i += np) {
        int k1 = i >> 8, n1 = i & 255;
        w1t[n1 * IN_DIM + k1] = __float2half(W1[i]);
        int k2 = i >> 7, n2 = i & 127;
        w2t[n2 * C1 + k2] = __float2half(W2[i]);
    }
    for (int i = tid; i < ET; i += np) {
        int d = (i < N_EDGES) ? dst[i] : i - N_EDGES;
        atomicAdd(&cnt[d], 1);
    }
}

// ================= CSR scan + scatter =================
__global__ void scan_local(const int* __restrict__ cnt, int* __restrict__ lscan,
                           int* __restrict__ bsum) {
    __shared__ int wsum[16];
    const int t = threadIdx.x, lane = t & 63, wv = t >> 6;
    int idx = blockIdx.x * SCAN_B + t;
    int v = (idx < N_NODES) ? cnt[idx] : 0;
    int sc = v;
#pragma unroll
    for (int o = 1; o < 64; o <<= 1) {
        int u = __shfl_up(sc, o);
        if (lane >= o) sc += u;
    }
    if (lane == 63) wsum[wv] = sc;
    __syncthreads();
    if (t == 0) {
        int run = 0;
#pragma unroll
        for (int w = 0; w < 16; ++w) { int s = wsum[w]; wsum[w] = run; run += s; }
        bsum[blockIdx.x] = run;
    }
    __syncthreads();
    if (idx < N_NODES) lscan[idx] = sc + wsum[wv];  // inclusive within block
}

__global__ void scan_bsum(int* __restrict__ bsum) {  // 1 block, 64 thr
    const int t = threadIdx.x;
    int v = (t < NSCB) ? bsum[t] : 0;
    int sc = v;
#pragma unroll
    for (int o = 1; o < 64; o <<= 1) {
        int u = __shfl_up(sc, o);
        if (t >= o) sc += u;
    }
    if (t < NSCB) bsum[t] = sc - v;  // exclusive
}

__global__ void scan_final(const int* __restrict__ cnt, const int* __restrict__ lscan,
                           const int* __restrict__ bsum, int* __restrict__ rp,
                           int* __restrict__ cursor) {
    int idx = blockIdx.x * SCAN_B + threadIdx.x;
    if (idx == 0) rp[0] = 0;
    if (idx >= N_NODES) return;
    int inc = lscan[idx] + bsum[idx >> 10];
    rp[idx + 1] = inc;
    cursor[idx] = inc - cnt[idx];
}

__global__ void scatter_kernel(const int* __restrict__ src, const int* __restrict__ dst,
                               int* __restrict__ cursor, int* __restrict__ col_src) {
    int i = blockIdx.x * blockDim.x + threadIdx.x;
    if (i >= ET) return;
    int s, d;
    if (i < N_EDGES) { s = src[i]; d = dst[i]; } else { s = d = i - N_EDGES; }
    int pos = atomicAdd(&cursor[d], 1);
    col_src[pos] = s;
}

// ================= GEMM1 (MFMA fp16) + fused attention dots =================
// h written PAIR-MAJOR: hpm[pair][node][128] fp16 (12.8 MB per head-pair table).
// as1/ad1 written pair-major float2: asp[pair*N + node] = {a_head2p, a_head2p+1}.
__global__ __launch_bounds__(256) void gemm1_mfma(
        const float* __restrict__ x, const __half* __restrict__ w1t,
        const float* __restrict__ aws, const float* __restrict__ awd,
        __half* __restrict__ hpm, float* __restrict__ as1m, float* __restrict__ ad1m) {
    const int tile = blockIdx.x * 4 + (threadIdx.x >> 6);
    if (tile >= MTILES) return;
    const int lane = threadIdx.x & 63;
    const int m0 = tile * 16, lm = lane & 15, lq = lane >> 4;
    h8 afrag[4];
    const float4* xrow = (const float4*)(x + (size_t)(m0 + lm) * IN_DIM + lq * 8);
#pragma unroll
    for (int kt = 0; kt < 4; ++kt) {
        float4 a = xrow[kt * 8];
        float4 b = xrow[kt * 8 + 1];
        union { h8 v; __half2 p[4]; } u;
        u.p[0] = __floats2half2_rn(a.x, a.y);
        u.p[1] = __floats2half2_rn(a.z, a.w);
        u.p[2] = __floats2half2_rn(b.x, b.y);
        u.p[3] = __floats2half2_rn(b.z, b.w);
        afrag[kt] = u.v;
    }
    f4 acc[16];
#pragma unroll
    for (int nt = 0; nt < 16; ++nt) acc[nt] = (f4){0.f, 0.f, 0.f, 0.f};
#pragma unroll
    for (int nt = 0; nt < 16; ++nt) {
        const h8* brow = (const h8*)(w1t + (size_t)(nt * 16 + lm) * IN_DIM + lq * 8);
#pragma unroll
        for (int kt = 0; kt < 4; ++kt)
            acc[nt] = __builtin_amdgcn_mfma_f32_16x16x32_f16(afrag[kt], brow[kt * 4],
                                                             acc[nt], 0, 0, 0);
    }
    float sS[4][4] = {{0.f}}, sD[4][4] = {{0.f}};
#pragma unroll
    for (int nt = 0; nt < 16; ++nt) {
        int col = nt * 16 + lm;
        float wa = aws[col], wd = awd[col];
        int hd = nt >> 2;           // head = col >> 6
        int pr = nt >> 3;           // pair = col >> 7
        int cip = col & 127;        // col within pair row
#pragma unroll
        for (int r = 0; r < 4; ++r) {
            float v = acc[nt][r];
            hpm[((size_t)pr * N_NODES + (m0 + lq * 4 + r)) * 128 + cip] = __float2half(v);
            sS[hd][r] += v * wa;
            sD[hd][r] += v * wd;
        }
    }
#pragma unroll
    for (int o = 1; o < 16; o <<= 1) {
#pragma unroll
        for (int hd = 0; hd < 4; ++hd)
#pragma unroll
            for (int r = 0; r < 4; ++r) {
                sS[hd][r] += __shfl_xor(sS[hd][r], o);
                sD[hd][r] += __shfl_xor(sD[hd][r], o);
            }
    }
    if (lm == 0) {
        float2* asp = (float2*)as1m;
        float2* adp = (float2*)ad1m;
#pragma unroll
        for (int r = 0; r < 4; ++r) {
            int row = m0 + lq * 4 + r;
            asp[row]           = make_float2(sS[0][r], sS[1][r]);   // pair 0
            asp[N_NODES + row] = make_float2(sS[2][r], sS[3][r]);   // pair 1
            adp[row]           = make_float2(sD[0][r], sD[1][r]);
            adp[N_NODES + row] = make_float2(sD[2][r], sD[3][r]);
        }
    }
}

// ================= GEMM2 (MFMA fp16) + fused attention dots (1 head) =================
// h2 written COLUMN-HALF-major: h2c[half][node][64] fp16 (6.4 MB per half table).
__global__ __launch_bounds__(256) void gemm2_mfma(
        const __half* __restrict__ ah, const __half* __restrict__ w2t,
        const float* __restrict__ aws, const float* __restrict__ awd,
        __half* __restrict__ h2c, float* __restrict__ as2, float* __restrict__ ad2) {
    const int tile = blockIdx.x * 4 + (threadIdx.x >> 6);
    if (tile >= MTILES) return;
    const int lane = threadIdx.x & 63;
    const int m0 = tile * 16, lm = lane & 15, lq = lane >> 4;
    h8 afrag[8];
    const h8* arow = (const h8*)(ah + (size_t)(m0 + lm) * C1 + lq * 8);
#pragma unroll
    for (int kt = 0; kt < 8; ++kt) afrag[kt] = arow[kt * 4];
    f4 acc[8];
#pragma unroll
    for (int nt = 0; nt < 8; ++nt) acc[nt] = (f4){0.f, 0.f, 0.f, 0.f};
#pragma unroll
    for (int nt = 0; nt < 8; ++nt) {
        const h8* brow = (const h8*)(w2t + (size_t)(nt * 16 + lm) * C1 + lq * 8);
#pragma unroll
        for (int kt = 0; kt < 8; ++kt)
            acc[nt] = __builtin_amdgcn_mfma_f32_16x16x32_f16(afrag[kt], brow[kt * 4],
                                                             acc[nt], 0, 0, 0);
    }
    float sS[4] = {0.f, 0.f, 0.f, 0.f}, sD[4] = {0.f, 0.f, 0.f, 0.f};
#pragma unroll
    for (int nt = 0; nt < 8; ++nt) {
        int col = nt * 16 + lm;
        float wa = aws[col], wd = awd[col];
        int half = nt >> 2;         // col >> 6
        int cih = col & 63;         // col within half row
#pragma unroll
        for (int r = 0; r < 4; ++r) {
            float v = acc[nt][r];
            h2c[((size_t)half * N_NODES + (m0 + lq * 4 + r)) * 64 + cih] = __float2half(v);
            sS[r] += v * wa;
            sD[r] += v * wd;
        }
    }
#pragma unroll
    for (int o = 1; o < 16; o <<= 1) {
#pragma unroll
        for (int r = 0; r < 4; ++r) {
            sS[r] += __shfl_xor(sS[r], o);
            sD[r] += __shfl_xor(sD[r], o);
        }
    }
    if (lm == 0) {
#pragma unroll
        for (int r = 0; r < 4; ++r) {
            int row = m0 + lq * 4 + r;
            as2[row] = sS[r];
            ad2[row] = sD[r];
        }
    }
}

// ================= fused softmax + aggregate, layer 1, HEAD-PAIR SPLIT =================
// (unchanged from round 3: measured 59.6 us, FETCH 166 MB)
__global__ __launch_bounds__(256) void aggregate1_fused(
        const int* __restrict__ rp, const int* __restrict__ cs,
        const __half* __restrict__ hpm, const float* __restrict__ as1m,
        const float* __restrict__ ad1m, const float* __restrict__ b1,
        __half* __restrict__ out1h) {
    __shared__ int4 stg[8][32];      // [halfwave][edge] = {row byte off, a_h0, a_h1, pad}
    const int pair = blockIdx.x & 1, g = blockIdx.x >> 1;
    const int hw = threadIdx.x >> 5, li = threadIdx.x & 31;
    const int d = g * 8 + hw;
    const int e0 = rp[d], deg = rp[d + 1] - e0;  // deg >= 1 (self-loop)
    const float2* asb = (const float2*)as1m + (size_t)pair * N_NODES;
    const float2 adv = ((const float2*)ad1m)[(size_t)pair * N_NODES + d];
    const char* hb = (const char*)hpm + (size_t)pair * N_NODES * 256;
    const int es = li >> 4, fl = li & 15;
    const int hip = fl >> 3;         // head within pair owning this lane's 8 feats
    const int lbyte = fl * 16;       // 8 fp16 = 16 B; 16 lanes cover the 256-B row
    float acc[8] = {0.f, 0.f, 0.f, 0.f, 0.f, 0.f, 0.f, 0.f};
    float ds0 = 0.f, ds1 = 0.f;
    for (int c0 = 0; c0 < deg; c0 += 32) {
        const int clen = min(32, deg - c0);
        int idx = c0 + li;
        bool valid = idx < deg;
        int s = valid ? cs[e0 + idx] : 0;
        float2 av = asb[s];
        float x0 = valid ? __expf(leaky(av.x + adv.x)) : 0.f;
        float x1 = valid ? __expf(leaky(av.y + adv.y)) : 0.f;
        stg[hw][li] = make_int4(s << 8, __float_as_int(x0), __float_as_int(x1), 0);
        ds0 += x0; ds1 += x1;
        __builtin_amdgcn_wave_barrier();  // DS in-order per wave; block compiler reordering
        int j = 0;
        for (; j + 8 <= clen; j += 8) {   // 8 edges per iteration, 4 loads in flight
            int4 p0 = stg[hw][j + es];
            int4 p1 = stg[hw][j + 2 + es];
            int4 p2 = stg[hw][j + 4 + es];
            int4 p3 = stg[hw][j + 6 + es];
            h8 v0 = *(const h8*)(hb + p0.x + lbyte);
            h8 v1 = *(const h8*)(hb + p1.x + lbyte);
            h8 v2 = *(const h8*)(hb + p2.x + lbyte);
            h8 v3 = *(const h8*)(hb + p3.x + lbyte);
            fma_mix8(acc, v0, __int_as_float(hip ? p0.z : p0.y));
            fma_mix8(acc, v1, __int_as_float(hip ? p1.z : p1.y));
            fma_mix8(acc, v2, __int_as_float(hip ? p2.z : p2.y));
            fma_mix8(acc, v3, __int_as_float(hip ? p3.z : p3.y));
        }
        for (; j < clen; j += 2) {
            // slots up to 31 always initialized (alpha=0 when invalid) -> safe
            int4 p0 = stg[hw][j + es];
            h8 v0 = *(const h8*)(hb + p0.x + lbyte);
            fma_mix8(acc, v0, __int_as_float(hip ? p0.z : p0.y));
        }
        __builtin_amdgcn_wave_barrier();
    }
    // combine the 2 edge-slot groups (mask 16 stays within the 32-lane half)
#pragma unroll
    for (int f = 0; f < 8; ++f) acc[f] += __shfl_xor(acc[f], 16);
#pragma unroll
    for (int o = 16; o > 0; o >>= 1) {
        ds0 += __shfl_xor(ds0, o);
        ds1 += __shfl_xor(ds1, o);
    }
    if (es == 0) {                   // lanes 0..15 of the half-wave
        float den = hip ? ds1 : ds0;
        float inv = 1.0f / (den + 1e-16f);
        float4 bA = ((const float4*)b1)[pair * 32 + fl * 2];
        float4 bB = ((const float4*)b1)[pair * 32 + fl * 2 + 1];
        h8 o;
        o[0] = (_Float16)elu(acc[0] * inv + bA.x);
        o[1] = (_Float16)elu(acc[1] * inv + bA.y);
        o[2] = (_Float16)elu(acc[2] * inv + bA.z);
        o[3] = (_Float16)elu(acc[3] * inv + bA.w);
        o[4] = (_Float16)elu(acc[4] * inv + bB.x);
        o[5] = (_Float16)elu(acc[5] * inv + bB.y);
        o[6] = (_Float16)elu(acc[6] * inv + bB.z);
        o[7] = (_Float16)elu(acc[7] * inv + bB.w);
        *(h8*)((char*)out1h + (size_t)d * 512 + pair * 256 + lbyte) = o;
    }
}

// ========== fused softmax + aggregate + bias, layer 2, COLUMN-HALF SPLIT ==========
// half = blockIdx & 1 -> each XCD touches one 6.4-MB column-half table (fits L2).
// 100k units (safe count). Half-wave: 4 edge-slots x 8 feat-lanes; 4 loads in flight.
// Writes post-bias values to out and atomicAdds the partial sum-of-squares to ss[d]
// (exactly 2 fp adds per row -> deterministic). norm_kernel finishes the L2 norm.
__global__ __launch_bounds__(256) void aggregate2_half(
        const int* __restrict__ rp, const int* __restrict__ cs,
        const __half* __restrict__ h2c, const float* __restrict__ as2,
        const float* __restrict__ ad2, const float* __restrict__ b2,
        float* __restrict__ out, float* __restrict__ ss) {
    __shared__ int2 stg[8][32];      // [halfwave][edge] = {row byte offset, alpha bits}
    const int half = blockIdx.x & 1, g = blockIdx.x >> 1;
    const int hw = threadIdx.x >> 5, li = threadIdx.x & 31;
    const int d = g * 8 + hw;
    const int e0 = rp[d], deg = rp[d + 1] - e0;
    const float adv = ad2[d];
    const char* hb = (const char*)h2c + (size_t)half * N_NODES * 128;
    const int es = li >> 3, fl = li & 7;
    const int lbyte = fl * 16;       // 8 fp16 = 16 B; 8 lanes cover the 128-B half row
    float acc[8] = {0.f, 0.f, 0.f, 0.f, 0.f, 0.f, 0.f, 0.f};
    float dsum = 0.f;
    for (int c0 = 0; c0 < deg; c0 += 32) {
        const int clen = min(32, deg - c0);
        int idx = c0 + li;
        bool valid = idx < deg;
        int s = valid ? cs[e0 + idx] : 0;
        float xv = valid ? __expf(leaky(as2[s] + adv)) : 0.f;
        stg[hw][li] = make_int2(s << 7, __float_as_int(xv));  // half row = 128 B
        dsum += xv;
        __builtin_amdgcn_wave_barrier();
        int j = 0;
        for (; j + 16 <= clen; j += 16) { // 16 edges per iteration, 4 loads in flight
            int2 p0 = stg[hw][j + es];
            int2 p1 = stg[hw][j + 4 + es];
            int2 p2 = stg[hw][j + 8 + es];
            int2 p3 = stg[hw][j + 12 + es];
            h8 v0 = *(const h8*)(hb + p0.x + lbyte);
            h8 v1 = *(const h8*)(hb + p1.x + lbyte);
            h8 v2 = *(const h8*)(hb + p2.x + lbyte);
            h8 v3 = *(const h8*)(hb + p3.x + lbyte);
            fma_mix8(acc, v0, __int_as_float(p0.y));
            fma_mix8(acc, v1, __int_as_float(p1.y));
            fma_mix8(acc, v2, __int_as_float(p2.y));
            fma_mix8(acc, v3, __int_as_float(p3.y));
        }
        for (; j < clen; j += 4) {
            // slots up to 31 always initialized (alpha=0 when invalid) -> safe
            int2 p0 = stg[hw][j + es];
            h8 v0 = *(const h8*)(hb + p0.x + lbyte);
            fma_mix8(acc, v0, __int_as_float(p0.y));
        }
        __builtin_amdgcn_wave_barrier();
    }
    // combine the 4 edge-slot groups (masks 8,16 stay within the 32-lane half)
#pragma unroll
    for (int f = 0; f < 8; ++f) {
        acc[f] += __shfl_xor(acc[f], 8);
        acc[f] += __shfl_xor(acc[f], 16);
    }
#pragma unroll
    for (int o = 16; o > 0; o >>= 1) dsum += __shfl_xor(dsum, o);
    if (es == 0) {                   // lanes 0..7 of the half-wave
        float inv = 1.0f / (dsum + 1e-16f);
        float4 bA = ((const float4*)b2)[half * 16 + fl * 2];
        float4 bB = ((const float4*)b2)[half * 16 + fl * 2 + 1];
        float v0 = acc[0] * inv + bA.x, v1 = acc[1] * inv + bA.y;
        float v2 = acc[2] * inv + bA.z, v3 = acc[3] * inv + bA.w;
        float v4 = acc[4] * inv + bB.x, v5 = acc[5] * inv + bB.y;
        float v6 = acc[6] * inv + bB.z, v7 = acc[7] * inv + bB.w;
        float sp = v0 * v0 + v1 * v1 + v2 * v2 + v3 * v3 +
                   v4 * v4 + v5 * v5 + v6 * v6 + v7 * v7;
#pragma unroll
        for (int o = 1; o < 8; o <<= 1) sp += __shfl_xor(sp, o);  // over the 8 fl lanes
        if (fl == 0) atomicAdd(&ss[d], sp);
        float4* orow = (float4*)(out + (size_t)d * OUT_DIM + half * 64 + fl * 8);
        orow[0] = make_float4(v0, v1, v2, v3);
        orow[1] = make_float4(v4, v5, v6, v7);
    }
}

// ================= final L2 normalize =================
__global__ __launch_bounds__(256) void norm_kernel(const float* __restrict__ ss,
                                                   float* __restrict__ out) {
    int idx = blockIdx.x * 256 + threadIdx.x;     // 50000*32 float4 slots
    int row = idx >> 5, c = idx & 31;
    if (row >= N_NODES) return;
    float sc = 1.0f / fmaxf(sqrtf(ss[row]), 1e-12f);
    float4* p = (float4*)out + (size_t)row * 32 + c;
    float4 v = *p;
    *p = make_float4(v.x * sc, v.y * sc, v.z * sc, v.w * sc);
}

extern "C" void kernel_launch(void* const* d_in, const int* in_sizes, int n_in,
                              void* d_out, int out_size, void* d_ws, size_t ws_size,
                              hipStream_t stream) {
    const float* x     = (const float*)d_in[0];
    const int*   edge  = (const int*)d_in[1];
    const int*   src   = edge;
    const int*   dst   = edge + N_EDGES;
    const float* W1    = (const float*)d_in[2];
    const float* aw_s1 = (const float*)d_in[3];
    const float* aw_d1 = (const float*)d_in[4];
    const float* b1    = (const float*)d_in[5];
    const float* W2    = (const float*)d_in[6];
    const float* aw_s2 = (const float*)d_in[7];
    const float* aw_d2 = (const float*)d_in[8];
    const float* b2    = (const float*)d_in[9];
    float* out = (float*)d_out;

    // ---- workspace layout ----
    char* ws = (char*)d_ws;
    size_t off = 0;
    auto alloc = [&](size_t bytes) {
        void* p = ws + off;
        off += (bytes + 255) & ~(size_t)255;
        return p;
    };
    int*    col_src = (int*)alloc((size_t)ET * 4);                  // 3.4 MB
    int*    rp     = (int*)alloc((size_t)(N_NODES + 1) * 4);
    int*    cursor = (int*)alloc((size_t)N_NODES * 4);
    int*    cnt    = (int*)alloc((size_t)N_NODES * 4);
    float*  ss     = (float*)alloc((size_t)N_NODES * 4);            // contiguous after cnt
    int*    lscan  = (int*)alloc((size_t)NSCB * SCAN_B * 4);
    int*    bsum   = (int*)alloc((size_t)NSCB * 4);
    float*  as1    = (float*)alloc((size_t)N_NODES * HEADS * 4);    // pair-major float2
    float*  ad1    = (float*)alloc((size_t)N_NODES * HEADS * 4);    // pair-major float2
    float*  as2    = (float*)alloc((size_t)N_NODES * 4);
    float*  ad2    = (float*)alloc((size_t)N_NODES * 4);
    __half* w1t    = (__half*)alloc((size_t)IN_DIM * C1 * 2);
    __half* w2t    = (__half*)alloc((size_t)C1 * OUT_DIM * 2);
    __half* hpm    = (__half*)alloc((size_t)N_NODES * C1 * 2);      // 25.6 MB pair-major (reused as h2c)
    __half* out1h  = (__half*)alloc((size_t)N_NODES * C1 * 2);      // 25.6 MB node-major
    __half* h2c    = hpm;  // layer-1 pair tables dead after aggregate1
    (void)off;

    // cnt (atomic histogram) and ss (atomic sumsq) need zeroing; they are adjacent.
    const size_t cnt_rounded = ((size_t)N_NODES * 4 + 255) & ~(size_t)255;
    hipMemsetAsync(cnt, 0, cnt_rounded + (size_t)N_NODES * 4, stream);

    const int egrid = (ET + 255) / 256;

    // ---- prep (weight transpose + histogram) + CSR build ----
    prep_kernel<<<1024, 256, 0, stream>>>(W1, W2, dst, w1t, w2t, cnt);
    scan_local<<<NSCB, SCAN_B, 0, stream>>>(cnt, lscan, bsum);
    scan_bsum<<<1, 64, 0, stream>>>(bsum);
    scan_final<<<NSCB, SCAN_B, 0, stream>>>(cnt, lscan, bsum, rp, cursor);
    scatter_kernel<<<egrid, 256, 0, stream>>>(src, dst, cursor, col_src);

    // ---- layer 1 ----
    gemm1_mfma<<<(MTILES + 3) / 4, 256, 0, stream>>>(x, w1t, aw_s1, aw_d1, hpm, as1, ad1);
    aggregate1_fused<<<(N_NODES / 8) * 2, 256, 0, stream>>>(rp, col_src, hpm, as1, ad1, b1, out1h);

    // ---- layer 2 ----
    gemm2_mfma<<<(MTILES + 3) / 4, 256, 0, stream>>>(out1h, w2t, aw_s2, aw_d2, h2c, as2, ad2);
    aggregate2_half<<<(N_NODES / 8) * 2, 256, 0, stream>>>(rp, col_src, h2c, as2, ad2, b2, out, ss);
    norm_kernel<<<(N_NODES * 32 + 255) / 256, 256, 0, stream>>>(ss, out);
}

// Round 6
// 332.110 us; speedup vs baseline: 1.1733x; 1.0959x over previous
//
#include <hip/hip_runtime.h>
#include <hip/hip_fp16.h>
#include <math.h>

#define N_NODES 50000
#define N_EDGES 800000
#define ET (N_EDGES + N_NODES)   // edges + self-loops
#define IN_DIM 128
#define HID 64
#define HEADS 4
#define C1 (HEADS * HID)         // 256
#define OUT_DIM 128
#define NEG_SLOPE 0.2f
#define MTILES 3125              // 50000 / 16 row-tiles
#define SCAN_B 1024
#define NSCB 49                  // ceil(50000/1024)
#define SCB 3328                 // scatter sub-blocks in fused kernel (>= ceil(ET/256))
#define FUSED_GRID 4160          // 832 gemm1 groups + 3328 scatter blocks, interleaved 1:4

typedef _Float16 h8 __attribute__((ext_vector_type(8)));
typedef float f4 __attribute__((ext_vector_type(4)));
typedef unsigned short u16;

__device__ __forceinline__ float leaky(float v) { return fmaxf(v, NEG_SLOPE * v); }
__device__ __forceinline__ float elu(float v) { return v > 0.0f ? v : expm1f(v); }

// One v_fma_mix_f32 per feature: acc.f32 += h.f16 * w.f32 (no extract/convert insts)
__device__ __forceinline__ void fma_mix8(float* acc, h8 v, float w) {
    union { h8 h; int i[4]; } u; u.h = v;
#pragma unroll
    for (int k = 0; k < 4; ++k) {
        asm("v_fma_mix_f32 %0, %1, %2, %0 op_sel:[0,0,0] op_sel_hi:[1,0,0]"
            : "+v"(acc[2 * k]) : "v"(u.i[k]), "v"(w));
        asm("v_fma_mix_f32 %0, %1, %2, %0 op_sel:[1,0,0] op_sel_hi:[1,0,0]"
            : "+v"(acc[2 * k + 1]) : "v"(u.i[k]), "v"(w));
    }
}

// ================= prep: weight transpose->fp16 + dst histogram =================
__global__ void prep_kernel(const float* __restrict__ W1, const float* __restrict__ W2,
                            const int* __restrict__ dst, __half* __restrict__ w1t,
                            __half* __restrict__ w2t, int* __restrict__ cnt) {
    const int tid = blockIdx.x * blockDim.x + threadIdx.x;
    const int np = gridDim.x * blockDim.x;
    for (int i = tid; i < IN_DIM * C1; i += np) {
        int k1 = i >> 8, n1 = i & 255;
        w1t[n1 * IN_DIM + k1] = __float2half(W1[i]);
        int k2 = i >> 7, n2 = i & 127;
        w2t[n2 * C1 + k2] = __float2half(W2[i]);
    }
    for (int i = tid; i < ET; i += np) {
        int d = (i < N_EDGES) ? dst[i] : i - N_EDGES;
        atomicAdd(&cnt[d], 1);
    }
}

// ================= CSR scan =================
__global__ void scan_local(const int* __restrict__ cnt, int* __restrict__ lscan,
                           int* __restrict__ bsum) {
    __shared__ int wsum[16];
    const int t = threadIdx.x, lane = t & 63, wv = t >> 6;
    int idx = blockIdx.x * SCAN_B + t;
    int v = (idx < N_NODES) ? cnt[idx] : 0;
    int sc = v;
#pragma unroll
    for (int o = 1; o < 64; o <<= 1) {
        int u = __shfl_up(sc, o);
        if (lane >= o) sc += u;
    }
    if (lane == 63) wsum[wv] = sc;
    __syncthreads();
    if (t == 0) {
        int run = 0;
#pragma unroll
        for (int w = 0; w < 16; ++w) { int s = wsum[w]; wsum[w] = run; run += s; }
        bsum[blockIdx.x] = run;
    }
    __syncthreads();
    if (idx < N_NODES) lscan[idx] = sc + wsum[wv];  // inclusive within block
}

__global__ void scan_bsum(int* __restrict__ bsum) {  // 1 block, 64 thr
    const int t = threadIdx.x;
    int v = (t < NSCB) ? bsum[t] : 0;
    int sc = v;
#pragma unroll
    for (int o = 1; o < 64; o <<= 1) {
        int u = __shfl_up(sc, o);
        if (t >= o) sc += u;
    }
    if (t < NSCB) bsum[t] = sc - v;  // exclusive
}

__global__ void scan_final(const int* __restrict__ cnt, const int* __restrict__ lscan,
                           const int* __restrict__ bsum, int* __restrict__ rp,
                           int* __restrict__ cursor) {
    int idx = blockIdx.x * SCAN_B + threadIdx.x;
    if (idx == 0) rp[0] = 0;
    if (idx >= N_NODES) return;
    int inc = lscan[idx] + bsum[idx >> 10];
    rp[idx + 1] = inc;
    cursor[idx] = inc - cnt[idx];
}

// ========== FUSED: scatter (atomic/latency-bound) || GEMM1 (MFMA-bound) ==========
// Interleaved block roles (1 gemm1 group : 4 scatter blocks) so both co-reside on
// the CUs from dispatch start. gemm1 is independent of the CSR chain; scatter needs
// cursor (scan_final) -> this kernel runs after scan_final.
// GEMM1 writes h PAIR-MAJOR: hpm[pair][node][128] fp16 (12.8 MB per head-pair
// table); as1/ad1 pair-major float2.
__global__ __launch_bounds__(256) void gemm1_scatter(
        const float* __restrict__ x, const __half* __restrict__ w1t,
        const float* __restrict__ aws, const float* __restrict__ awd,
        __half* __restrict__ hpm, float* __restrict__ as1m, float* __restrict__ ad1m,
        const int* __restrict__ src, const int* __restrict__ dst,
        int* __restrict__ cursor, u16* __restrict__ cs16) {
    const int q5 = blockIdx.x / 5, r5 = blockIdx.x % 5;
    if (r5 != 0) {
        // ---- scatter role: sub-block si in [0, SCB) ----
        int si = q5 * 4 + (r5 - 1);
        int i = si * 256 + threadIdx.x;
        if (i < ET) {
            int s, d;
            if (i < N_EDGES) { s = src[i]; d = dst[i]; } else { s = d = i - N_EDGES; }
            int pos = atomicAdd(&cursor[d], 1);
            cs16[pos] = (u16)s;          // src < 50000 fits u16
        }
        return;
    }
    // ---- gemm1 role: tile group q5 (4 waves -> 4 row-tiles) ----
    const int tile = q5 * 4 + (threadIdx.x >> 6);
    if (tile >= MTILES) return;
    const int lane = threadIdx.x & 63;
    const int m0 = tile * 16, lm = lane & 15, lq = lane >> 4;
    h8 afrag[4];
    const float4* xrow = (const float4*)(x + (size_t)(m0 + lm) * IN_DIM + lq * 8);
#pragma unroll
    for (int kt = 0; kt < 4; ++kt) {
        float4 a = xrow[kt * 8];
        float4 b = xrow[kt * 8 + 1];
        union { h8 v; __half2 p[4]; } u;
        u.p[0] = __floats2half2_rn(a.x, a.y);
        u.p[1] = __floats2half2_rn(a.z, a.w);
        u.p[2] = __floats2half2_rn(b.x, b.y);
        u.p[3] = __floats2half2_rn(b.z, b.w);
        afrag[kt] = u.v;
    }
    f4 acc[16];
#pragma unroll
    for (int nt = 0; nt < 16; ++nt) acc[nt] = (f4){0.f, 0.f, 0.f, 0.f};
#pragma unroll
    for (int nt = 0; nt < 16; ++nt) {
        const h8* brow = (const h8*)(w1t + (size_t)(nt * 16 + lm) * IN_DIM + lq * 8);
#pragma unroll
        for (int kt = 0; kt < 4; ++kt)
            acc[nt] = __builtin_amdgcn_mfma_f32_16x16x32_f16(afrag[kt], brow[kt * 4],
                                                             acc[nt], 0, 0, 0);
    }
    float sS[4][4] = {{0.f}}, sD[4][4] = {{0.f}};
#pragma unroll
    for (int nt = 0; nt < 16; ++nt) {
        int col = nt * 16 + lm;
        float wa = aws[col], wd = awd[col];
        int hd = nt >> 2;           // head = col >> 6
        int pr = nt >> 3;           // pair = col >> 7
        int cip = col & 127;        // col within pair row
#pragma unroll
        for (int r = 0; r < 4; ++r) {
            float v = acc[nt][r];
            hpm[((size_t)pr * N_NODES + (m0 + lq * 4 + r)) * 128 + cip] = __float2half(v);
            sS[hd][r] += v * wa;
            sD[hd][r] += v * wd;
        }
    }
#pragma unroll
    for (int o = 1; o < 16; o <<= 1) {
#pragma unroll
        for (int hd = 0; hd < 4; ++hd)
#pragma unroll
            for (int r = 0; r < 4; ++r) {
                sS[hd][r] += __shfl_xor(sS[hd][r], o);
                sD[hd][r] += __shfl_xor(sD[hd][r], o);
            }
    }
    if (lm == 0) {
        float2* asp = (float2*)as1m;
        float2* adp = (float2*)ad1m;
#pragma unroll
        for (int r = 0; r < 4; ++r) {
            int row = m0 + lq * 4 + r;
            asp[row]           = make_float2(sS[0][r], sS[1][r]);   // pair 0
            asp[N_NODES + row] = make_float2(sS[2][r], sS[3][r]);   // pair 1
            adp[row]           = make_float2(sD[0][r], sD[1][r]);
            adp[N_NODES + row] = make_float2(sD[2][r], sD[3][r]);
        }
    }
}

// ================= GEMM2 (MFMA fp16) + fused attention dots (1 head) =================
// (r3 node-major version: measured best configuration)
__global__ __launch_bounds__(256) void gemm2_mfma(
        const __half* __restrict__ ah, const __half* __restrict__ w2t,
        const float* __restrict__ aws, const float* __restrict__ awd,
        __half* __restrict__ h, float* __restrict__ as2, float* __restrict__ ad2) {
    const int tile = blockIdx.x * 4 + (threadIdx.x >> 6);
    if (tile >= MTILES) return;
    const int lane = threadIdx.x & 63;
    const int m0 = tile * 16, lm = lane & 15, lq = lane >> 4;
    h8 afrag[8];
    const h8* arow = (const h8*)(ah + (size_t)(m0 + lm) * C1 + lq * 8);
#pragma unroll
    for (int kt = 0; kt < 8; ++kt) afrag[kt] = arow[kt * 4];
    f4 acc[8];
#pragma unroll
    for (int nt = 0; nt < 8; ++nt) acc[nt] = (f4){0.f, 0.f, 0.f, 0.f};
#pragma unroll
    for (int nt = 0; nt < 8; ++nt) {
        const h8* brow = (const h8*)(w2t + (size_t)(nt * 16 + lm) * C1 + lq * 8);
#pragma unroll
        for (int kt = 0; kt < 8; ++kt)
            acc[nt] = __builtin_amdgcn_mfma_f32_16x16x32_f16(afrag[kt], brow[kt * 4],
                                                             acc[nt], 0, 0, 0);
    }
    float sS[4] = {0.f, 0.f, 0.f, 0.f}, sD[4] = {0.f, 0.f, 0.f, 0.f};
#pragma unroll
    for (int nt = 0; nt < 8; ++nt) {
        int col = nt * 16 + lm;
        float wa = aws[col], wd = awd[col];
#pragma unroll
        for (int r = 0; r < 4; ++r) {
            float v = acc[nt][r];
            h[(size_t)(m0 + lq * 4 + r) * OUT_DIM + col] = __float2half(v);
            sS[r] += v * wa;
            sD[r] += v * wd;
        }
    }
#pragma unroll
    for (int o = 1; o < 16; o <<= 1) {
#pragma unroll
        for (int r = 0; r < 4; ++r) {
            sS[r] += __shfl_xor(sS[r], o);
            sD[r] += __shfl_xor(sD[r], o);
        }
    }
    if (lm == 0) {
#pragma unroll
        for (int r = 0; r < 4; ++r) {
            int row = m0 + lq * 4 + r;
            as2[row] = sS[r];
            ad2[row] = sD[r];
        }
    }
}

// ================= fused softmax + aggregate, layer 1, HEAD-PAIR SPLIT =================
// (r3 structure; cs as u16; gather pipeline deepened to 8 loads in flight)
__global__ __launch_bounds__(256) void aggregate1_fused(
        const int* __restrict__ rp, const u16* __restrict__ cs16,
        const __half* __restrict__ hpm, const float* __restrict__ as1m,
        const float* __restrict__ ad1m, const float* __restrict__ b1,
        __half* __restrict__ out1h) {
    __shared__ int4 stg[8][32];      // [halfwave][edge] = {row byte off, a_h0, a_h1, pad}
    const int pair = blockIdx.x & 1, g = blockIdx.x >> 1;
    const int hw = threadIdx.x >> 5, li = threadIdx.x & 31;
    const int d = g * 8 + hw;
    const int e0 = rp[d], deg = rp[d + 1] - e0;  // deg >= 1 (self-loop)
    const float2* asb = (const float2*)as1m + (size_t)pair * N_NODES;
    const float2 adv = ((const float2*)ad1m)[(size_t)pair * N_NODES + d];
    const char* hb = (const char*)hpm + (size_t)pair * N_NODES * 256;
    const int es = li >> 4, fl = li & 15;
    const int hip = fl >> 3;         // head within pair owning this lane's 8 feats
    const int lbyte = fl * 16;       // 8 fp16 = 16 B; 16 lanes cover the 256-B row
    float acc[8] = {0.f, 0.f, 0.f, 0.f, 0.f, 0.f, 0.f, 0.f};
    float ds0 = 0.f, ds1 = 0.f;
    for (int c0 = 0; c0 < deg; c0 += 32) {
        const int clen = min(32, deg - c0);
        int idx = c0 + li;
        bool valid = idx < deg;
        int s = valid ? (int)cs16[e0 + idx] : 0;
        float2 av = asb[s];
        float x0 = valid ? __expf(leaky(av.x + adv.x)) : 0.f;
        float x1 = valid ? __expf(leaky(av.y + adv.y)) : 0.f;
        stg[hw][li] = make_int4(s << 8, __float_as_int(x0), __float_as_int(x1), 0);
        ds0 += x0; ds1 += x1;
        __builtin_amdgcn_wave_barrier();  // DS in-order per wave; block compiler reordering
        int j = 0;
        for (; j + 16 <= clen; j += 16) { // 16 edges per iteration, 8 loads in flight
            int4 p0 = stg[hw][j + es];
            int4 p1 = stg[hw][j + 2 + es];
            int4 p2 = stg[hw][j + 4 + es];
            int4 p3 = stg[hw][j + 6 + es];
            int4 p4 = stg[hw][j + 8 + es];
            int4 p5 = stg[hw][j + 10 + es];
            int4 p6 = stg[hw][j + 12 + es];
            int4 p7 = stg[hw][j + 14 + es];
            h8 v0 = *(const h8*)(hb + p0.x + lbyte);
            h8 v1 = *(const h8*)(hb + p1.x + lbyte);
            h8 v2 = *(const h8*)(hb + p2.x + lbyte);
            h8 v3 = *(const h8*)(hb + p3.x + lbyte);
            h8 v4 = *(const h8*)(hb + p4.x + lbyte);
            h8 v5 = *(const h8*)(hb + p5.x + lbyte);
            h8 v6 = *(const h8*)(hb + p6.x + lbyte);
            h8 v7 = *(const h8*)(hb + p7.x + lbyte);
            fma_mix8(acc, v0, __int_as_float(hip ? p0.z : p0.y));
            fma_mix8(acc, v1, __int_as_float(hip ? p1.z : p1.y));
            fma_mix8(acc, v2, __int_as_float(hip ? p2.z : p2.y));
            fma_mix8(acc, v3, __int_as_float(hip ? p3.z : p3.y));
            fma_mix8(acc, v4, __int_as_float(hip ? p4.z : p4.y));
            fma_mix8(acc, v5, __int_as_float(hip ? p5.z : p5.y));
            fma_mix8(acc, v6, __int_as_float(hip ? p6.z : p6.y));
            fma_mix8(acc, v7, __int_as_float(hip ? p7.z : p7.y));
        }
        for (; j + 8 <= clen; j += 8) {   // 8 edges, 4 loads in flight
            int4 p0 = stg[hw][j + es];
            int4 p1 = stg[hw][j + 2 + es];
            int4 p2 = stg[hw][j + 4 + es];
            int4 p3 = stg[hw][j + 6 + es];
            h8 v0 = *(const h8*)(hb + p0.x + lbyte);
            h8 v1 = *(const h8*)(hb + p1.x + lbyte);
            h8 v2 = *(const h8*)(hb + p2.x + lbyte);
            h8 v3 = *(const h8*)(hb + p3.x + lbyte);
            fma_mix8(acc, v0, __int_as_float(hip ? p0.z : p0.y));
            fma_mix8(acc, v1, __int_as_float(hip ? p1.z : p1.y));
            fma_mix8(acc, v2, __int_as_float(hip ? p2.z : p2.y));
            fma_mix8(acc, v3, __int_as_float(hip ? p3.z : p3.y));
        }
        for (; j < clen; j += 2) {
            // slots up to 31 always initialized (alpha=0 when invalid) -> safe
            int4 p0 = stg[hw][j + es];
            h8 v0 = *(const h8*)(hb + p0.x + lbyte);
            fma_mix8(acc, v0, __int_as_float(hip ? p0.z : p0.y));
        }
        __builtin_amdgcn_wave_barrier();
    }
    // combine the 2 edge-slot groups (mask 16 stays within the 32-lane half)
#pragma unroll
    for (int f = 0; f < 8; ++f) acc[f] += __shfl_xor(acc[f], 16);
#pragma unroll
    for (int o = 16; o > 0; o >>= 1) {
        ds0 += __shfl_xor(ds0, o);
        ds1 += __shfl_xor(ds1, o);
    }
    if (es == 0) {                   // lanes 0..15 of the half-wave
        float den = hip ? ds1 : ds0;
        float inv = 1.0f / (den + 1e-16f);
        float4 bA = ((const float4*)b1)[pair * 32 + fl * 2];
        float4 bB = ((const float4*)b1)[pair * 32 + fl * 2 + 1];
        h8 o;
        o[0] = (_Float16)elu(acc[0] * inv + bA.x);
        o[1] = (_Float16)elu(acc[1] * inv + bA.y);
        o[2] = (_Float16)elu(acc[2] * inv + bA.z);
        o[3] = (_Float16)elu(acc[3] * inv + bA.w);
        o[4] = (_Float16)elu(acc[4] * inv + bB.x);
        o[5] = (_Float16)elu(acc[5] * inv + bB.y);
        o[6] = (_Float16)elu(acc[6] * inv + bB.z);
        o[7] = (_Float16)elu(acc[7] * inv + bB.w);
        *(h8*)((char*)out1h + (size_t)d * 512 + pair * 256 + lbyte) = o;
    }
}

// ================= fused softmax + aggregate + bias + L2-normalize, layer 2 ======
// (r3 node-major version; cs as u16; gather pipeline deepened to 8 loads in flight)
__global__ __launch_bounds__(256) void aggregate2_fused(
        const int* __restrict__ rp, const u16* __restrict__ cs16,
        const __half* __restrict__ h2h, const float* __restrict__ as2,
        const float* __restrict__ ad2, const float* __restrict__ b2,
        float* __restrict__ out) {
    __shared__ int2 stg[8][32];      // [halfwave][edge] = {row byte offset, alpha bits}
    const int hw = threadIdx.x >> 5, li = threadIdx.x & 31;
    const int d = blockIdx.x * 8 + hw;
    const int e0 = rp[d], deg = rp[d + 1] - e0;
    const float adv = ad2[d];
    const int q = li >> 4, lo = li & 15;
    const int lbyte = lo * 16;       // 8 fp16
    const char* hbase = (const char*)h2h;
    float acc[8] = {0.f, 0.f, 0.f, 0.f, 0.f, 0.f, 0.f, 0.f};
    float dsum = 0.f;
    for (int c0 = 0; c0 < deg; c0 += 32) {
        const int clen = min(32, deg - c0);
        int idx = c0 + li;
        bool valid = idx < deg;
        int s = valid ? (int)cs16[e0 + idx] : 0;
        float xv = valid ? __expf(leaky(as2[s] + adv)) : 0.f;
        stg[hw][li] = make_int2(s << 8, __float_as_int(xv));  // row = 256 B
        dsum += xv;
        __builtin_amdgcn_wave_barrier();
        int j = 0;
        for (; j + 16 <= clen; j += 16) { // 16 edges per iteration, 8 loads in flight
            int2 p0 = stg[hw][j + q];
            int2 p1 = stg[hw][j + 2 + q];
            int2 p2 = stg[hw][j + 4 + q];
            int2 p3 = stg[hw][j + 6 + q];
            int2 p4 = stg[hw][j + 8 + q];
            int2 p5 = stg[hw][j + 10 + q];
            int2 p6 = stg[hw][j + 12 + q];
            int2 p7 = stg[hw][j + 14 + q];
            h8 v0 = *(const h8*)(hbase + p0.x + lbyte);
            h8 v1 = *(const h8*)(hbase + p1.x + lbyte);
            h8 v2 = *(const h8*)(hbase + p2.x + lbyte);
            h8 v3 = *(const h8*)(hbase + p3.x + lbyte);
            h8 v4 = *(const h8*)(hbase + p4.x + lbyte);
            h8 v5 = *(const h8*)(hbase + p5.x + lbyte);
            h8 v6 = *(const h8*)(hbase + p6.x + lbyte);
            h8 v7 = *(const h8*)(hbase + p7.x + lbyte);
            fma_mix8(acc, v0, __int_as_float(p0.y));
            fma_mix8(acc, v1, __int_as_float(p1.y));
            fma_mix8(acc, v2, __int_as_float(p2.y));
            fma_mix8(acc, v3, __int_as_float(p3.y));
            fma_mix8(acc, v4, __int_as_float(p4.y));
            fma_mix8(acc, v5, __int_as_float(p5.y));
            fma_mix8(acc, v6, __int_as_float(p6.y));
            fma_mix8(acc, v7, __int_as_float(p7.y));
        }
        for (; j + 8 <= clen; j += 8) {   // 8 edges, 4 loads in flight
            int2 p0 = stg[hw][j + q];
            int2 p1 = stg[hw][j + 2 + q];
            int2 p2 = stg[hw][j + 4 + q];
            int2 p3 = stg[hw][j + 6 + q];
            h8 v0 = *(const h8*)(hbase + p0.x + lbyte);
            h8 v1 = *(const h8*)(hbase + p1.x + lbyte);
            h8 v2 = *(const h8*)(hbase + p2.x + lbyte);
            h8 v3 = *(const h8*)(hbase + p3.x + lbyte);
            fma_mix8(acc, v0, __int_as_float(p0.y));
            fma_mix8(acc, v1, __int_as_float(p1.y));
            fma_mix8(acc, v2, __int_as_float(p2.y));
            fma_mix8(acc, v3, __int_as_float(p3.y));
        }
        for (; j < clen; j += 2) {
            int2 p0 = stg[hw][j + q];
            h8 v0 = *(const h8*)(hbase + p0.x + lbyte);
            fma_mix8(acc, v0, __int_as_float(p0.y));
        }
        __builtin_amdgcn_wave_barrier();
    }
#pragma unroll
    for (int f = 0; f < 8; ++f) acc[f] += __shfl_xor(acc[f], 16);  // combine q=0/1
#pragma unroll
    for (int o = 16; o > 0; o >>= 1) dsum += __shfl_xor(dsum, o);
    if (q == 0) {
        float inv = 1.0f / (dsum + 1e-16f);
        float4 bA = ((const float4*)b2)[lo * 2];
        float4 bB = ((const float4*)b2)[lo * 2 + 1];
        float v0 = acc[0] * inv + bA.x, v1 = acc[1] * inv + bA.y;
        float v2 = acc[2] * inv + bA.z, v3 = acc[3] * inv + bA.w;
        float v4 = acc[4] * inv + bB.x, v5 = acc[5] * inv + bB.y;
        float v6 = acc[6] * inv + bB.z, v7 = acc[7] * inv + bB.w;
        float ss = v0 * v0 + v1 * v1 + v2 * v2 + v3 * v3 +
                   v4 * v4 + v5 * v5 + v6 * v6 + v7 * v7;
#pragma unroll
        for (int o = 1; o < 16; o <<= 1) ss += __shfl_xor(ss, o);  // lanes lo 0-15 group
        float sc = 1.0f / fmaxf(sqrtf(ss), 1e-12f);
        float4* orow = (float4*)((char*)out + (size_t)d * 512 + lo * 32);
        orow[0] = make_float4(v0 * sc, v1 * sc, v2 * sc, v3 * sc);
        orow[1] = make_float4(v4 * sc, v5 * sc, v6 * sc, v7 * sc);
    }
}

extern "C" void kernel_launch(void* const* d_in, const int* in_sizes, int n_in,
                              void* d_out, int out_size, void* d_ws, size_t ws_size,
                              hipStream_t stream) {
    const float* x     = (const float*)d_in[0];
    const int*   edge  = (const int*)d_in[1];
    const int*   src   = edge;
    const int*   dst   = edge + N_EDGES;
    const float* W1    = (const float*)d_in[2];
    const float* aw_s1 = (const float*)d_in[3];
    const float* aw_d1 = (const float*)d_in[4];
    const float* b1    = (const float*)d_in[5];
    const float* W2    = (const float*)d_in[6];
    const float* aw_s2 = (const float*)d_in[7];
    const float* aw_d2 = (const float*)d_in[8];
    const float* b2    = (const float*)d_in[9];
    float* out = (float*)d_out;

    // ---- workspace layout ----
    char* ws = (char*)d_ws;
    size_t off = 0;
    auto alloc = [&](size_t bytes) {
        void* p = ws + off;
        off += (bytes + 255) & ~(size_t)255;
        return p;
    };
    u16*    cs16   = (u16*)alloc((size_t)ET * 2);                   // 1.7 MB
    int*    rp     = (int*)alloc((size_t)(N_NODES + 1) * 4);
    int*    cursor = (int*)alloc((size_t)N_NODES * 4);
    int*    cnt    = (int*)alloc((size_t)N_NODES * 4);
    int*    lscan  = (int*)alloc((size_t)NSCB * SCAN_B * 4);
    int*    bsum   = (int*)alloc((size_t)NSCB * 4);
    float*  as1    = (float*)alloc((size_t)N_NODES * HEADS * 4);    // pair-major float2
    float*  ad1    = (float*)alloc((size_t)N_NODES * HEADS * 4);    // pair-major float2
    float*  as2    = (float*)alloc((size_t)N_NODES * 4);
    float*  ad2    = (float*)alloc((size_t)N_NODES * 4);
    __half* w1t    = (__half*)alloc((size_t)IN_DIM * C1 * 2);
    __half* w2t    = (__half*)alloc((size_t)C1 * OUT_DIM * 2);
    __half* hpm    = (__half*)alloc((size_t)N_NODES * C1 * 2);      // 25.6 MB pair-major (reused as h2h)
    __half* out1h  = (__half*)alloc((size_t)N_NODES * C1 * 2);      // 25.6 MB node-major
    __half* h2h    = hpm;  // layer-1 pair tables dead after aggregate1
    (void)off;

    // Only cnt needs zeroing (atomic histogram).
    hipMemsetAsync(cnt, 0, (size_t)N_NODES * 4, stream);

    // ---- prep (weight transpose + histogram) + CSR scan ----
    prep_kernel<<<1024, 256, 0, stream>>>(W1, W2, dst, w1t, w2t, cnt);
    scan_local<<<NSCB, SCAN_B, 0, stream>>>(cnt, lscan, bsum);
    scan_bsum<<<1, 64, 0, stream>>>(bsum);
    scan_final<<<NSCB, SCAN_B, 0, stream>>>(cnt, lscan, bsum, rp, cursor);

    // ---- fused: CSR scatter || GEMM1 (independent workloads overlapped) ----
    gemm1_scatter<<<FUSED_GRID, 256, 0, stream>>>(x, w1t, aw_s1, aw_d1, hpm, as1, ad1,
                                                  src, dst, cursor, cs16);

    // ---- layer 1 aggregate ----
    aggregate1_fused<<<(N_NODES / 8) * 2, 256, 0, stream>>>(rp, cs16, hpm, as1, ad1, b1, out1h);

    // ---- layer 2 ----
    gemm2_mfma<<<(MTILES + 3) / 4, 256, 0, stream>>>(out1h, w2t, aw_s2, aw_d2, h2h, as2, ad2);
    aggregate2_fused<<<N_NODES / 8, 256, 0, stream>>>(rp, cs16, h2h, as2, ad2, b2, out);
}

// Round 7
// 310.167 us; speedup vs baseline: 1.2563x; 1.0707x over previous
//
#include <hip/hip_runtime.h>
#include <hip/hip_fp16.h>
#include <math.h>

#define N_NODES 50000
#define N_EDGES 800000
#define ET (N_EDGES + N_NODES)   // edges + self-loops
#define IN_DIM 128
#define HID 64
#define HEADS 4
#define C1 (HEADS * HID)         // 256
#define OUT_DIM 128
#define NEG_SLOPE 0.2f
#define MTILES 3125              // 50000 / 16 row-tiles
#define SCAN_B 1024
#define NSCB 49                  // ceil(50000/1024)

typedef _Float16 h8 __attribute__((ext_vector_type(8)));
typedef float f4 __attribute__((ext_vector_type(4)));
typedef unsigned short u16;

__device__ __forceinline__ float leaky(float v) { return fmaxf(v, NEG_SLOPE * v); }
__device__ __forceinline__ float elu(float v) { return v > 0.0f ? v : expm1f(v); }

// One v_fma_mix_f32 per feature: acc.f32 += h.f16 * w.f32 (no extract/convert insts)
__device__ __forceinline__ void fma_mix8(float* acc, h8 v, float w) {
    union { h8 h; int i[4]; } u; u.h = v;
#pragma unroll
    for (int k = 0; k < 4; ++k) {
        asm("v_fma_mix_f32 %0, %1, %2, %0 op_sel:[0,0,0] op_sel_hi:[1,0,0]"
            : "+v"(acc[2 * k]) : "v"(u.i[k]), "v"(w));
        asm("v_fma_mix_f32 %0, %1, %2, %0 op_sel:[1,0,0] op_sel_hi:[1,0,0]"
            : "+v"(acc[2 * k + 1]) : "v"(u.i[k]), "v"(w));
    }
}

// ====== prep: weight transpose->fp16 + dst histogram WITH rank capture ======
// atomicAdd's return value IS this edge's rank within its dst node -> stored in
// rank16, which makes the subsequent scatter atomic-free. Self-loops are excluded
// (scan adds the implicit +1; self-loop occupies slot rp[d+1]-1).
__global__ void prep_kernel(const float* __restrict__ W1, const float* __restrict__ W2,
                            const int* __restrict__ dst, __half* __restrict__ w1t,
                            __half* __restrict__ w2t, int* __restrict__ cnt,
                            u16* __restrict__ rank16) {
    const int tid = blockIdx.x * blockDim.x + threadIdx.x;
    const int np = gridDim.x * blockDim.x;
    for (int i = tid; i < IN_DIM * C1; i += np) {
        int k1 = i >> 8, n1 = i & 255;
        w1t[n1 * IN_DIM + k1] = __float2half(W1[i]);
        int k2 = i >> 7, n2 = i & 127;
        w2t[n2 * C1 + k2] = __float2half(W2[i]);
    }
    for (int i = tid; i < N_EDGES; i += np) {
        int d = dst[i];
        rank16[i] = (u16)atomicAdd(&cnt[d], 1);
    }
}

// ================= CSR scan (counts get +1 for the implicit self-loop) =========
__global__ void scan_local(const int* __restrict__ cnt, int* __restrict__ lscan,
                           int* __restrict__ bsum) {
    __shared__ int wsum[16];
    const int t = threadIdx.x, lane = t & 63, wv = t >> 6;
    int idx = blockIdx.x * SCAN_B + t;
    int v = (idx < N_NODES) ? cnt[idx] + 1 : 0;   // +1 = self-loop
    int sc = v;
#pragma unroll
    for (int o = 1; o < 64; o <<= 1) {
        int u = __shfl_up(sc, o);
        if (lane >= o) sc += u;
    }
    if (lane == 63) wsum[wv] = sc;
    __syncthreads();
    if (t == 0) {
        int run = 0;
#pragma unroll
        for (int w = 0; w < 16; ++w) { int s = wsum[w]; wsum[w] = run; run += s; }
        bsum[blockIdx.x] = run;
    }
    __syncthreads();
    if (idx < N_NODES) lscan[idx] = sc + wsum[wv];  // inclusive within block
}

__global__ void scan_bsum(int* __restrict__ bsum) {  // 1 block, 64 thr
    const int t = threadIdx.x;
    int v = (t < NSCB) ? bsum[t] : 0;
    int sc = v;
#pragma unroll
    for (int o = 1; o < 64; o <<= 1) {
        int u = __shfl_up(sc, o);
        if (t >= o) sc += u;
    }
    if (t < NSCB) bsum[t] = sc - v;  // exclusive
}

__global__ void scan_final(const int* __restrict__ lscan, const int* __restrict__ bsum,
                           int* __restrict__ rp) {
    int idx = blockIdx.x * SCAN_B + threadIdx.x;
    if (idx == 0) rp[0] = 0;
    if (idx >= N_NODES) return;
    rp[idx + 1] = lscan[idx] + bsum[idx >> 10];
}

// ============ scatter, ATOMIC-FREE: pos = rp[d] + precomputed rank ============
__global__ void scatter_plain(const int* __restrict__ src, const int* __restrict__ dst,
                              const u16* __restrict__ rank16, const int* __restrict__ rp,
                              u16* __restrict__ cs16) {
    int i = blockIdx.x * blockDim.x + threadIdx.x;
    if (i >= ET) return;
    if (i < N_EDGES) {
        int d = dst[i];
        cs16[rp[d] + (int)rank16[i]] = (u16)src[i];
    } else {
        int d = i - N_EDGES;
        cs16[rp[d + 1] - 1] = (u16)d;      // self-loop in the last slot
    }
}

// ================= GEMM1 (MFMA fp16) + fused attention dots =================
// h written PAIR-MAJOR: hpm[pair][node][128] fp16 (12.8 MB per head-pair table).
// as1/ad1 written pair-major float2.
__global__ __launch_bounds__(256) void gemm1_mfma(
        const float* __restrict__ x, const __half* __restrict__ w1t,
        const float* __restrict__ aws, const float* __restrict__ awd,
        __half* __restrict__ hpm, float* __restrict__ as1m, float* __restrict__ ad1m) {
    const int tile = blockIdx.x * 4 + (threadIdx.x >> 6);
    if (tile >= MTILES) return;
    const int lane = threadIdx.x & 63;
    const int m0 = tile * 16, lm = lane & 15, lq = lane >> 4;
    h8 afrag[4];
    const float4* xrow = (const float4*)(x + (size_t)(m0 + lm) * IN_DIM + lq * 8);
#pragma unroll
    for (int kt = 0; kt < 4; ++kt) {
        float4 a = xrow[kt * 8];
        float4 b = xrow[kt * 8 + 1];
        union { h8 v; __half2 p[4]; } u;
        u.p[0] = __floats2half2_rn(a.x, a.y);
        u.p[1] = __floats2half2_rn(a.z, a.w);
        u.p[2] = __floats2half2_rn(b.x, b.y);
        u.p[3] = __floats2half2_rn(b.z, b.w);
        afrag[kt] = u.v;
    }
    f4 acc[16];
#pragma unroll
    for (int nt = 0; nt < 16; ++nt) acc[nt] = (f4){0.f, 0.f, 0.f, 0.f};
#pragma unroll
    for (int nt = 0; nt < 16; ++nt) {
        const h8* brow = (const h8*)(w1t + (size_t)(nt * 16 + lm) * IN_DIM + lq * 8);
#pragma unroll
        for (int kt = 0; kt < 4; ++kt)
            acc[nt] = __builtin_amdgcn_mfma_f32_16x16x32_f16(afrag[kt], brow[kt * 4],
                                                             acc[nt], 0, 0, 0);
    }
    float sS[4][4] = {{0.f}}, sD[4][4] = {{0.f}};
#pragma unroll
    for (int nt = 0; nt < 16; ++nt) {
        int col = nt * 16 + lm;
        float wa = aws[col], wd = awd[col];
        int hd = nt >> 2;           // head = col >> 6
        int pr = nt >> 3;           // pair = col >> 7
        int cip = col & 127;        // col within pair row
#pragma unroll
        for (int r = 0; r < 4; ++r) {
            float v = acc[nt][r];
            hpm[((size_t)pr * N_NODES + (m0 + lq * 4 + r)) * 128 + cip] = __float2half(v);
            sS[hd][r] += v * wa;
            sD[hd][r] += v * wd;
        }
    }
#pragma unroll
    for (int o = 1; o < 16; o <<= 1) {
#pragma unroll
        for (int hd = 0; hd < 4; ++hd)
#pragma unroll
            for (int r = 0; r < 4; ++r) {
                sS[hd][r] += __shfl_xor(sS[hd][r], o);
                sD[hd][r] += __shfl_xor(sD[hd][r], o);
            }
    }
    if (lm == 0) {
        float2* asp = (float2*)as1m;
        float2* adp = (float2*)ad1m;
#pragma unroll
        for (int r = 0; r < 4; ++r) {
            int row = m0 + lq * 4 + r;
            asp[row]           = make_float2(sS[0][r], sS[1][r]);   // pair 0
            asp[N_NODES + row] = make_float2(sS[2][r], sS[3][r]);   // pair 1
            adp[row]           = make_float2(sD[0][r], sD[1][r]);
            adp[N_NODES + row] = make_float2(sD[2][r], sD[3][r]);
        }
    }
}

// ================= GEMM2 (MFMA fp16) + fused attention dots (1 head) =================
__global__ __launch_bounds__(256) void gemm2_mfma(
        const __half* __restrict__ ah, const __half* __restrict__ w2t,
        const float* __restrict__ aws, const float* __restrict__ awd,
        __half* __restrict__ h, float* __restrict__ as2, float* __restrict__ ad2) {
    const int tile = blockIdx.x * 4 + (threadIdx.x >> 6);
    if (tile >= MTILES) return;
    const int lane = threadIdx.x & 63;
    const int m0 = tile * 16, lm = lane & 15, lq = lane >> 4;
    h8 afrag[8];
    const h8* arow = (const h8*)(ah + (size_t)(m0 + lm) * C1 + lq * 8);
#pragma unroll
    for (int kt = 0; kt < 8; ++kt) afrag[kt] = arow[kt * 4];
    f4 acc[8];
#pragma unroll
    for (int nt = 0; nt < 8; ++nt) acc[nt] = (f4){0.f, 0.f, 0.f, 0.f};
#pragma unroll
    for (int nt = 0; nt < 8; ++nt) {
        const h8* brow = (const h8*)(w2t + (size_t)(nt * 16 + lm) * C1 + lq * 8);
#pragma unroll
        for (int kt = 0; kt < 8; ++kt)
            acc[nt] = __builtin_amdgcn_mfma_f32_16x16x32_f16(afrag[kt], brow[kt * 4],
                                                             acc[nt], 0, 0, 0);
    }
    float sS[4] = {0.f, 0.f, 0.f, 0.f}, sD[4] = {0.f, 0.f, 0.f, 0.f};
#pragma unroll
    for (int nt = 0; nt < 8; ++nt) {
        int col = nt * 16 + lm;
        float wa = aws[col], wd = awd[col];
#pragma unroll
        for (int r = 0; r < 4; ++r) {
            float v = acc[nt][r];
            h[(size_t)(m0 + lq * 4 + r) * OUT_DIM + col] = __float2half(v);
            sS[r] += v * wa;
            sD[r] += v * wd;
        }
    }
#pragma unroll
    for (int o = 1; o < 16; o <<= 1) {
#pragma unroll
        for (int r = 0; r < 4; ++r) {
            sS[r] += __shfl_xor(sS[r], o);
            sD[r] += __shfl_xor(sD[r], o);
        }
    }
    if (lm == 0) {
#pragma unroll
        for (int r = 0; r < 4; ++r) {
            int row = m0 + lq * 4 + r;
            as2[row] = sS[r];
            ad2[row] = sD[r];
        }
    }
}

// ================= fused softmax + aggregate, layer 1, HEAD-PAIR SPLIT =================
// (r6 version: u16 cs, 8 loads in flight)
__global__ __launch_bounds__(256) void aggregate1_fused(
        const int* __restrict__ rp, const u16* __restrict__ cs16,
        const __half* __restrict__ hpm, const float* __restrict__ as1m,
        const float* __restrict__ ad1m, const float* __restrict__ b1,
        __half* __restrict__ out1h) {
    __shared__ int4 stg[8][32];      // [halfwave][edge] = {row byte off, a_h0, a_h1, pad}
    const int pair = blockIdx.x & 1, g = blockIdx.x >> 1;
    const int hw = threadIdx.x >> 5, li = threadIdx.x & 31;
    const int d = g * 8 + hw;
    const int e0 = rp[d], deg = rp[d + 1] - e0;  // deg >= 1 (self-loop)
    const float2* asb = (const float2*)as1m + (size_t)pair * N_NODES;
    const float2 adv = ((const float2*)ad1m)[(size_t)pair * N_NODES + d];
    const char* hb = (const char*)hpm + (size_t)pair * N_NODES * 256;
    const int es = li >> 4, fl = li & 15;
    const int hip = fl >> 3;         // head within pair owning this lane's 8 feats
    const int lbyte = fl * 16;       // 8 fp16 = 16 B; 16 lanes cover the 256-B row
    float acc[8] = {0.f, 0.f, 0.f, 0.f, 0.f, 0.f, 0.f, 0.f};
    float ds0 = 0.f, ds1 = 0.f;
    for (int c0 = 0; c0 < deg; c0 += 32) {
        const int clen = min(32, deg - c0);
        int idx = c0 + li;
        bool valid = idx < deg;
        int s = valid ? (int)cs16[e0 + idx] : 0;
        float2 av = asb[s];
        float x0 = valid ? __expf(leaky(av.x + adv.x)) : 0.f;
        float x1 = valid ? __expf(leaky(av.y + adv.y)) : 0.f;
        stg[hw][li] = make_int4(s << 8, __float_as_int(x0), __float_as_int(x1), 0);
        ds0 += x0; ds1 += x1;
        __builtin_amdgcn_wave_barrier();  // DS in-order per wave; block compiler reordering
        int j = 0;
        for (; j + 16 <= clen; j += 16) { // 16 edges per iteration, 8 loads in flight
            int4 p0 = stg[hw][j + es];
            int4 p1 = stg[hw][j + 2 + es];
            int4 p2 = stg[hw][j + 4 + es];
            int4 p3 = stg[hw][j + 6 + es];
            int4 p4 = stg[hw][j + 8 + es];
            int4 p5 = stg[hw][j + 10 + es];
            int4 p6 = stg[hw][j + 12 + es];
            int4 p7 = stg[hw][j + 14 + es];
            h8 v0 = *(const h8*)(hb + p0.x + lbyte);
            h8 v1 = *(const h8*)(hb + p1.x + lbyte);
            h8 v2 = *(const h8*)(hb + p2.x + lbyte);
            h8 v3 = *(const h8*)(hb + p3.x + lbyte);
            h8 v4 = *(const h8*)(hb + p4.x + lbyte);
            h8 v5 = *(const h8*)(hb + p5.x + lbyte);
            h8 v6 = *(const h8*)(hb + p6.x + lbyte);
            h8 v7 = *(const h8*)(hb + p7.x + lbyte);
            fma_mix8(acc, v0, __int_as_float(hip ? p0.z : p0.y));
            fma_mix8(acc, v1, __int_as_float(hip ? p1.z : p1.y));
            fma_mix8(acc, v2, __int_as_float(hip ? p2.z : p2.y));
            fma_mix8(acc, v3, __int_as_float(hip ? p3.z : p3.y));
            fma_mix8(acc, v4, __int_as_float(hip ? p4.z : p4.y));
            fma_mix8(acc, v5, __int_as_float(hip ? p5.z : p5.y));
            fma_mix8(acc, v6, __int_as_float(hip ? p6.z : p6.y));
            fma_mix8(acc, v7, __int_as_float(hip ? p7.z : p7.y));
        }
        for (; j + 8 <= clen; j += 8) {   // 8 edges, 4 loads in flight
            int4 p0 = stg[hw][j + es];
            int4 p1 = stg[hw][j + 2 + es];
            int4 p2 = stg[hw][j + 4 + es];
            int4 p3 = stg[hw][j + 6 + es];
            h8 v0 = *(const h8*)(hb + p0.x + lbyte);
            h8 v1 = *(const h8*)(hb + p1.x + lbyte);
            h8 v2 = *(const h8*)(hb + p2.x + lbyte);
            h8 v3 = *(const h8*)(hb + p3.x + lbyte);
            fma_mix8(acc, v0, __int_as_float(hip ? p0.z : p0.y));
            fma_mix8(acc, v1, __int_as_float(hip ? p1.z : p1.y));
            fma_mix8(acc, v2, __int_as_float(hip ? p2.z : p2.y));
            fma_mix8(acc, v3, __int_as_float(hip ? p3.z : p3.y));
        }
        for (; j < clen; j += 2) {
            // slots up to 31 always initialized (alpha=0 when invalid) -> safe
            int4 p0 = stg[hw][j + es];
            h8 v0 = *(const h8*)(hb + p0.x + lbyte);
            fma_mix8(acc, v0, __int_as_float(hip ? p0.z : p0.y));
        }
        __builtin_amdgcn_wave_barrier();
    }
    // combine the 2 edge-slot groups (mask 16 stays within the 32-lane half)
#pragma unroll
    for (int f = 0; f < 8; ++f) acc[f] += __shfl_xor(acc[f], 16);
#pragma unroll
    for (int o = 16; o > 0; o >>= 1) {
        ds0 += __shfl_xor(ds0, o);
        ds1 += __shfl_xor(ds1, o);
    }
    if (es == 0) {                   // lanes 0..15 of the half-wave
        float den = hip ? ds1 : ds0;
        float inv = 1.0f / (den + 1e-16f);
        float4 bA = ((const float4*)b1)[pair * 32 + fl * 2];
        float4 bB = ((const float4*)b1)[pair * 32 + fl * 2 + 1];
        h8 o;
        o[0] = (_Float16)elu(acc[0] * inv + bA.x);
        o[1] = (_Float16)elu(acc[1] * inv + bA.y);
        o[2] = (_Float16)elu(acc[2] * inv + bA.z);
        o[3] = (_Float16)elu(acc[3] * inv + bA.w);
        o[4] = (_Float16)elu(acc[4] * inv + bB.x);
        o[5] = (_Float16)elu(acc[5] * inv + bB.y);
        o[6] = (_Float16)elu(acc[6] * inv + bB.z);
        o[7] = (_Float16)elu(acc[7] * inv + bB.w);
        *(h8*)((char*)out1h + (size_t)d * 512 + pair * 256 + lbyte) = o;
    }
}

// ================= fused softmax + aggregate + bias + L2-normalize, layer 2 ======
// (r6 version: u16 cs, 8 loads in flight)
__global__ __launch_bounds__(256) void aggregate2_fused(
        const int* __restrict__ rp, const u16* __restrict__ cs16,
        const __half* __restrict__ h2h, const float* __restrict__ as2,
        const float* __restrict__ ad2, const float* __restrict__ b2,
        float* __restrict__ out) {
    __shared__ int2 stg[8][32];      // [halfwave][edge] = {row byte offset, alpha bits}
    const int hw = threadIdx.x >> 5, li = threadIdx.x & 31;
    const int d = blockIdx.x * 8 + hw;
    const int e0 = rp[d], deg = rp[d + 1] - e0;
    const float adv = ad2[d];
    const int q = li >> 4, lo = li & 15;
    const int lbyte = lo * 16;       // 8 fp16
    const char* hbase = (const char*)h2h;
    float acc[8] = {0.f, 0.f, 0.f, 0.f, 0.f, 0.f, 0.f, 0.f};
    float dsum = 0.f;
    for (int c0 = 0; c0 < deg; c0 += 32) {
        const int clen = min(32, deg - c0);
        int idx = c0 + li;
        bool valid = idx < deg;
        int s = valid ? (int)cs16[e0 + idx] : 0;
        float xv = valid ? __expf(leaky(as2[s] + adv)) : 0.f;
        stg[hw][li] = make_int2(s << 8, __float_as_int(xv));  // row = 256 B
        dsum += xv;
        __builtin_amdgcn_wave_barrier();
        int j = 0;
        for (; j + 16 <= clen; j += 16) { // 16 edges per iteration, 8 loads in flight
            int2 p0 = stg[hw][j + q];
            int2 p1 = stg[hw][j + 2 + q];
            int2 p2 = stg[hw][j + 4 + q];
            int2 p3 = stg[hw][j + 6 + q];
            int2 p4 = stg[hw][j + 8 + q];
            int2 p5 = stg[hw][j + 10 + q];
            int2 p6 = stg[hw][j + 12 + q];
            int2 p7 = stg[hw][j + 14 + q];
            h8 v0 = *(const h8*)(hbase + p0.x + lbyte);
            h8 v1 = *(const h8*)(hbase + p1.x + lbyte);
            h8 v2 = *(const h8*)(hbase + p2.x + lbyte);
            h8 v3 = *(const h8*)(hbase + p3.x + lbyte);
            h8 v4 = *(const h8*)(hbase + p4.x + lbyte);
            h8 v5 = *(const h8*)(hbase + p5.x + lbyte);
            h8 v6 = *(const h8*)(hbase + p6.x + lbyte);
            h8 v7 = *(const h8*)(hbase + p7.x + lbyte);
            fma_mix8(acc, v0, __int_as_float(p0.y));
            fma_mix8(acc, v1, __int_as_float(p1.y));
            fma_mix8(acc, v2, __int_as_float(p2.y));
            fma_mix8(acc, v3, __int_as_float(p3.y));
            fma_mix8(acc, v4, __int_as_float(p4.y));
            fma_mix8(acc, v5, __int_as_float(p5.y));
            fma_mix8(acc, v6, __int_as_float(p6.y));
            fma_mix8(acc, v7, __int_as_float(p7.y));
        }
        for (; j + 8 <= clen; j += 8) {   // 8 edges, 4 loads in flight
            int2 p0 = stg[hw][j + q];
            int2 p1 = stg[hw][j + 2 + q];
            int2 p2 = stg[hw][j + 4 + q];
            int2 p3 = stg[hw][j + 6 + q];
            h8 v0 = *(const h8*)(hbase + p0.x + lbyte);
            h8 v1 = *(const h8*)(hbase + p1.x + lbyte);
            h8 v2 = *(const h8*)(hbase + p2.x + lbyte);
            h8 v3 = *(const h8*)(hbase + p3.x + lbyte);
            fma_mix8(acc, v0, __int_as_float(p0.y));
            fma_mix8(acc, v1, __int_as_float(p1.y));
            fma_mix8(acc, v2, __int_as_float(p2.y));
            fma_mix8(acc, v3, __int_as_float(p3.y));
        }
        for (; j < clen; j += 2) {
            int2 p0 = stg[hw][j + q];
            h8 v0 = *(const h8*)(hbase + p0.x + lbyte);
            fma_mix8(acc, v0, __int_as_float(p0.y));
        }
        __builtin_amdgcn_wave_barrier();
    }
#pragma unroll
    for (int f = 0; f < 8; ++f) acc[f] += __shfl_xor(acc[f], 16);  // combine q=0/1
#pragma unroll
    for (int o = 16; o > 0; o >>= 1) dsum += __shfl_xor(dsum, o);
    if (q == 0) {
        float inv = 1.0f / (dsum + 1e-16f);
        float4 bA = ((const float4*)b2)[lo * 2];
        float4 bB = ((const float4*)b2)[lo * 2 + 1];
        float v0 = acc[0] * inv + bA.x, v1 = acc[1] * inv + bA.y;
        float v2 = acc[2] * inv + bA.z, v3 = acc[3] * inv + bA.w;
        float v4 = acc[4] * inv + bB.x, v5 = acc[5] * inv + bB.y;
        float v6 = acc[6] * inv + bB.z, v7 = acc[7] * inv + bB.w;
        float ss = v0 * v0 + v1 * v1 + v2 * v2 + v3 * v3 +
                   v4 * v4 + v5 * v5 + v6 * v6 + v7 * v7;
#pragma unroll
        for (int o = 1; o < 16; o <<= 1) ss += __shfl_xor(ss, o);  // lanes lo 0-15 group
        float sc = 1.0f / fmaxf(sqrtf(ss), 1e-12f);
        float4* orow = (float4*)((char*)out + (size_t)d * 512 + lo * 32);
        orow[0] = make_float4(v0 * sc, v1 * sc, v2 * sc, v3 * sc);
        orow[1] = make_float4(v4 * sc, v5 * sc, v6 * sc, v7 * sc);
    }
}

extern "C" void kernel_launch(void* const* d_in, const int* in_sizes, int n_in,
                              void* d_out, int out_size, void* d_ws, size_t ws_size,
                              hipStream_t stream) {
    const float* x     = (const float*)d_in[0];
    const int*   edge  = (const int*)d_in[1];
    const int*   src   = edge;
    const int*   dst   = edge + N_EDGES;
    const float* W1    = (const float*)d_in[2];
    const float* aw_s1 = (const float*)d_in[3];
    const float* aw_d1 = (const float*)d_in[4];
    const float* b1    = (const float*)d_in[5];
    const float* W2    = (const float*)d_in[6];
    const float* aw_s2 = (const float*)d_in[7];
    const float* aw_d2 = (const float*)d_in[8];
    const float* b2    = (const float*)d_in[9];
    float* out = (float*)d_out;

    // ---- workspace layout ----
    char* ws = (char*)d_ws;
    size_t off = 0;
    auto alloc = [&](size_t bytes) {
        void* p = ws + off;
        off += (bytes + 255) & ~(size_t)255;
        return p;
    };
    u16*    cs16   = (u16*)alloc((size_t)ET * 2);                   // 1.7 MB
    u16*    rank16 = (u16*)alloc((size_t)N_EDGES * 2);              // 1.6 MB
    int*    rp     = (int*)alloc((size_t)(N_NODES + 1) * 4);
    int*    cnt    = (int*)alloc((size_t)N_NODES * 4);
    int*    lscan  = (int*)alloc((size_t)NSCB * SCAN_B * 4);
    int*    bsum   = (int*)alloc((size_t)NSCB * 4);
    float*  as1    = (float*)alloc((size_t)N_NODES * HEADS * 4);    // pair-major float2
    float*  ad1    = (float*)alloc((size_t)N_NODES * HEADS * 4);    // pair-major float2
    float*  as2    = (float*)alloc((size_t)N_NODES * 4);
    float*  ad2    = (float*)alloc((size_t)N_NODES * 4);
    __half* w1t    = (__half*)alloc((size_t)IN_DIM * C1 * 2);
    __half* w2t    = (__half*)alloc((size_t)C1 * OUT_DIM * 2);
    __half* hpm    = (__half*)alloc((size_t)N_NODES * C1 * 2);      // 25.6 MB pair-major (reused as h2h)
    __half* out1h  = (__half*)alloc((size_t)N_NODES * C1 * 2);      // 25.6 MB node-major
    __half* h2h    = hpm;  // layer-1 pair tables dead after aggregate1
    (void)off;

    // Only cnt needs zeroing (atomic histogram).
    hipMemsetAsync(cnt, 0, (size_t)N_NODES * 4, stream);

    const int egrid = (ET + 255) / 256;

    // ---- prep: transpose + histogram-with-rank (the ONLY atomic pass) ----
    prep_kernel<<<1024, 256, 0, stream>>>(W1, W2, dst, w1t, w2t, cnt, rank16);
    scan_local<<<NSCB, SCAN_B, 0, stream>>>(cnt, lscan, bsum);
    scan_bsum<<<1, 64, 0, stream>>>(bsum);
    scan_final<<<NSCB, SCAN_B, 0, stream>>>(lscan, bsum, rp);
    // ---- atomic-free scatter (plain stores via precomputed ranks) ----
    scatter_plain<<<egrid, 256, 0, stream>>>(src, dst, rank16, rp, cs16);

    // ---- layer 1 ----
    gemm1_mfma<<<(MTILES + 3) / 4, 256, 0, stream>>>(x, w1t, aw_s1, aw_d1, hpm, as1, ad1);
    aggregate1_fused<<<(N_NODES / 8) * 2, 256, 0, stream>>>(rp, cs16, hpm, as1, ad1, b1, out1h);

    // ---- layer 2 ----
    gemm2_mfma<<<(MTILES + 3) / 4, 256, 0, stream>>>(out1h, w2t, aw_s2, aw_d2, h2h, as2, ad2);
    aggregate2_fused<<<N_NODES / 8, 256, 0, stream>>>(rp, cs16, h2h, as2, ad2, b2, out);
}